// Round 9
// baseline (391.450 us; speedup 1.0000x reference)
//
#include <hip/hip_runtime.h>
#include <hip/hip_bf16.h>

typedef unsigned short u16;
typedef __attribute__((ext_vector_type(8))) short short8;   // 8 bf16 (4 VGPRs)
typedef __attribute__((ext_vector_type(4))) float f32x4;    // 4 fp32 acc

#define DM 1024      // d_model
#define HM 4096      // ffn hidden
#define NHEADS 16
#define HD 64        // head dim
#define SQ 2048      // seq len
#define NBATCH 2
#define NTOK 4096    // NBATCH*SQ

#define NX  ((size_t)NTOK * DM)

__device__ __forceinline__ u16 f2b(float f) {   // fp32 -> bf16 RNE
    union { float f; unsigned int i; } w; w.f = f;
    unsigned int x = w.i;
    return (u16)((x + 0x7FFFu + ((x >> 16) & 1u)) >> 16);
}

__device__ __forceinline__ void gload_lds16(const void* g, void* l) {
    __builtin_amdgcn_global_load_lds(
        (const __attribute__((address_space(1))) void*)g,
        (__attribute__((address_space(3))) void*)l, 16, 0, 0);
}

// ---- all weights fp32 -> bf16 + bias pack, ONE kernel ----
// dst layout (u16): wq|wk|wv (3M) | wo (1M) | w1 (4M) | w2 (4M)
__global__ void cvt_all(const float* __restrict__ wq, const float* __restrict__ wk,
                        const float* __restrict__ wv, const float* __restrict__ wo,
                        const float* __restrict__ w1, const float* __restrict__ w2,
                        const float* __restrict__ bq, const float* __restrict__ bk,
                        const float* __restrict__ bv, float* __restrict__ bias_dst,
                        u16* __restrict__ dst) {
    const int NW4 = DM * DM / 4;   // float4s per DMxDM matrix
    int i = blockIdx.x * 256 + threadIdx.x;
    if (i < 12 * NW4) {
        const float* src; int base; float sc = 1.0f;
        if      (i <     NW4) { src = wq; base = 0;       sc = 0.125f; }
        else if (i < 2 * NW4) { src = wk; base = NW4; }
        else if (i < 3 * NW4) { src = wv; base = 2 * NW4; }
        else if (i < 4 * NW4) { src = wo; base = 3 * NW4; }
        else if (i < 8 * NW4) { src = w1; base = 4 * NW4; }
        else                  { src = w2; base = 8 * NW4; }
        float4 f = ((const float4*)src)[i - base];
        ushort4 o;
        o.x = f2b(f.x * sc); o.y = f2b(f.y * sc);
        o.z = f2b(f.z * sc); o.w = f2b(f.w * sc);
        ((ushort4*)dst)[i] = o;
    } else {
        int j = i - 12 * NW4;
        if (j < 3 * DM) {
            float v = (j < DM) ? bq[j] * 0.125f
                    : (j < 2 * DM) ? bk[j - DM] : bv[j - 2 * DM];
            bias_dst[j] = v;
        }
    }
}

// ---------------- LayerNorm: fp32 in, fp32 + bf16 out ----------------
__global__ void ln_kernel(const float* __restrict__ xin, const float* __restrict__ g,
                          const float* __restrict__ b, float* __restrict__ outf,
                          u16* __restrict__ outb) {
    int t = blockIdx.x, tid = threadIdx.x;
    float4 f = ((const float4*)(xin + (size_t)t * DM))[tid];
    float v0 = f.x, v1 = f.y, v2 = f.z, v3 = f.w;
    float s  = v0 + v1 + v2 + v3;
    float ss = v0*v0 + v1*v1 + v2*v2 + v3*v3;
    #pragma unroll
    for (int o = 32; o > 0; o >>= 1) {
        s  += __shfl_down(s,  o, 64);
        ss += __shfl_down(ss, o, 64);
    }
    __shared__ float rs[4], rss[4];
    int w = tid >> 6, lane = tid & 63;
    if (!lane) { rs[w] = s; rss[w] = ss; }
    __syncthreads();
    s  = rs[0] + rs[1] + rs[2] + rs[3];
    ss = rss[0] + rss[1] + rss[2] + rss[3];
    float mean = s * (1.0f / DM);
    float var  = ss * (1.0f / DM) - mean * mean;
    float rstd = rsqrtf(var + 1e-5f);
    float4 gu = ((const float4*)g)[tid];
    float4 bu = ((const float4*)b)[tid];
    float4 o;
    o.x = (v0 - mean) * rstd * gu.x + bu.x;
    o.y = (v1 - mean) * rstd * gu.y + bu.y;
    o.z = (v2 - mean) * rstd * gu.z + bu.z;
    o.w = (v3 - mean) * rstd * gu.w + bu.w;
    ((float4*)(outf + (size_t)t * DM))[tid] = o;
    ushort4 ob; ob.x = f2b(o.x); ob.y = f2b(o.y); ob.z = f2b(o.z); ob.w = f2b(o.w);
    ((ushort4*)(outb + (size_t)t * DM))[tid] = ob;
}

// ---- V transpose: qkv V-region [tok][h*64+d] -> vT[b*16+h][d][tok_in_batch] ----
__global__ void vtr_kernel(const u16* __restrict__ qkv, u16* __restrict__ vT) {
    __shared__ u16 tile[64][72];
    int bid = blockIdx.x;          // 32 bh x 32 t-tiles
    int tt = bid & 31, bh = bid >> 5;
    int h = bh & (NHEADS - 1), b = bh >> 4;
    int tid = threadIdx.x;
    int r = tid >> 2, c0 = (tid & 3) << 4;
    const u16* src = qkv + ((size_t)(b * SQ + tt * 64 + r)) * (3 * DM) + 2 * DM + h * HD + c0;
    #pragma unroll
    for (int j = 0; j < 4; j++)
        *(ushort4*)&tile[r][c0 + (j << 2)] = *(const ushort4*)(src + (j << 2));
    __syncthreads();
    int dd = tid >> 2, t0 = (tid & 3) << 4;
    u16* dst = vT + ((size_t)bh * HD + dd) * SQ + tt * 64 + t0;
    #pragma unroll
    for (int j = 0; j < 4; j++) {
        ushort4 v;
        v.x = tile[t0 + (j << 2) + 0][dd];
        v.y = tile[t0 + (j << 2) + 1][dd];
        v.z = tile[t0 + (j << 2) + 2][dd];
        v.w = tile[t0 + (j << 2) + 3][dd];
        *(ushort4*)(dst + (j << 2)) = v;
    }
}

// ------- MFMA GEMM 128x128: 4-slot half-tile ring, counted vmcnt (T4) -------
// K split into 32-wide half-tiles staged into a 4-slot LDS ring [128][32] each.
// Per phase: vmcnt(counted) + raw s_barrier (NO vmcnt(0) drain in loop),
// prefetch hp+3, ds_read frags, 16 MFMA. Swizzle identical to fattn's proven
// [*][32] scheme: phys chunk = logical ^ ((row>>1)&3); staging pre-swizzles
// the global source (lsw), reads use fcs. 2-way bank aliasing = free.
template<int GELU, int RESID, int OUTBF>
__global__ __launch_bounds__(256, 2)
void gemm_bt(const u16* __restrict__ A, const u16* __restrict__ W,
             const float* __restrict__ bias, const float* __restrict__ resid,
             void* __restrict__ Cout, int M, int N, int K) {
    __shared__ __attribute__((aligned(16))) u16 As[4 * 128 * 32];   // 32 KB ring
    __shared__ __attribute__((aligned(16))) u16 Bs[4 * 128 * 32];   // 32 KB ring
    int tid  = threadIdx.x;
    int wid  = tid >> 6, lane = tid & 63;
    int m0 = blockIdx.y << 7, n0 = blockIdx.x << 7;
    int wm = (wid & 1) << 6, wn = (wid >> 1) << 6;

    int fr  = lane & 15;
    int fcs = (((lane >> 4) ^ ((fr >> 1) & 3)) << 3);   // frag read chunk (u16)
    int lsw = (((lane & 3) ^ ((lane >> 3) & 3)) << 3);  // staging source chunk
    int rStg = lane >> 2;                               // row in 16-row segment

    f32x4 acc[4][4];
    #pragma unroll
    for (int i = 0; i < 4; i++)
        #pragma unroll
        for (int j = 0; j < 4; j++)
            acc[i][j] = (f32x4){0.f, 0.f, 0.f, 0.f};

    const int NHP = K >> 5;   // half-phases (32 for K=1024)

    // prologue: stage half-tiles 0,1,2 into slots 0,1,2 (12 loads/thread)
    for (int hp = 0; hp < 3; hp++) {
        int k0 = hp << 5, so = (hp & 3) << 12;   // slot offset in u16
        #pragma unroll
        for (int t = 0; t < 2; t++) {
            int seg = (wid << 1) + t;
            int row = (seg << 4) + rStg;
            gload_lds16(A + (size_t)(m0 + row) * K + k0 + lsw, As + so + (seg << 9));
            gload_lds16(W + (size_t)(n0 + row) * K + k0 + lsw, Bs + so + (seg << 9));
        }
    }

    for (int hp = 0; hp < NHP; hp++) {
        // counted wait: half-tile hp complete; up to 2 half-tiles stay in flight
        if (hp + 3 <= NHP) {          // hp <= NHP-3: 8 loads may remain
            asm volatile("s_waitcnt vmcnt(8)" ::: "memory");
        } else if (hp + 2 == NHP) {   // hp == NHP-2: only last half-tile in flight
            asm volatile("s_waitcnt vmcnt(4)" ::: "memory");
        } else {                      // hp == NHP-1: nothing may remain
            asm volatile("s_waitcnt vmcnt(0)" ::: "memory");
        }
        __builtin_amdgcn_s_barrier();   // all waves' hp-loads done; hp-1 reads done
        if (hp + 3 < NHP) {             // prefetch half-tile hp+3 into its slot
            int k0 = (hp + 3) << 5, so = ((hp + 3) & 3) << 12;
            #pragma unroll
            for (int t = 0; t < 2; t++) {
                int seg = (wid << 1) + t;
                int row = (seg << 4) + rStg;
                gload_lds16(A + (size_t)(m0 + row) * K + k0 + lsw, As + so + (seg << 9));
                gload_lds16(W + (size_t)(n0 + row) * K + k0 + lsw, Bs + so + (seg << 9));
            }
        }
        int so = (hp & 3) << 12;
        short8 af[4], bf[4];
        #pragma unroll
        for (int mi = 0; mi < 4; mi++)
            af[mi] = *(const short8*)(As + so + (wm + (mi << 4) + fr) * 32 + fcs);
        #pragma unroll
        for (int ni = 0; ni < 4; ni++)
            bf[ni] = *(const short8*)(Bs + so + (wn + (ni << 4) + fr) * 32 + fcs);
        #pragma unroll
        for (int mi = 0; mi < 4; mi++)
            #pragma unroll
            for (int ni = 0; ni < 4; ni++)
                acc[mi][ni] = __builtin_amdgcn_mfma_f32_16x16x32_bf16(
                    af[mi], bf[ni], acc[mi][ni], 0, 0, 0);
    }

    int erow = (lane >> 4) << 2;
    #pragma unroll
    for (int ni = 0; ni < 4; ni++) {
        int col = n0 + wn + (ni << 4) + fr;
        float bv = bias[col];
        #pragma unroll
        for (int mi = 0; mi < 4; mi++) {
            #pragma unroll
            for (int r = 0; r < 4; r++) {
                int row = m0 + wm + (mi << 4) + erow + r;
                float val = acc[mi][ni][r] + bv;
                if (GELU)  val = 0.5f * val * (1.0f + erff(val * 0.70710678118654752f));
                if (RESID) val += resid[(size_t)row * N + col];
                if (OUTBF) ((u16*)Cout)[(size_t)row * N + col] = f2b(val);
                else       ((float*)Cout)[(size_t)row * N + col] = val;
            }
        }
    }
}

// ------- MFMA GEMM 128x64, BK=64, dbuf + 8-way XOR chunk swizzle -------
// XCD swizzle kept (R6-era; net-neutral-to-positive).
template<int GELU, int RESID, int OUTBF>
__global__ __launch_bounds__(256, 3)
void gemm_n64(const u16* __restrict__ A, const u16* __restrict__ W,
              const float* __restrict__ bias, const float* __restrict__ resid,
              void* __restrict__ Cout, int M, int N, int K) {
    __shared__ __attribute__((aligned(16))) u16 As[2 * 128 * 64];   // 32 KB
    __shared__ __attribute__((aligned(16))) u16 Bs[2 * 64 * 64];    // 16 KB
    int tid  = threadIdx.x;
    int wid  = tid >> 6, lane = tid & 63;
    int nwgx = gridDim.x;
    int bidl = blockIdx.y * nwgx + blockIdx.x;
    int cpx  = (nwgx * gridDim.y) >> 3;
    int swz  = (bidl & 7) * cpx + (bidl >> 3);
    int m0 = (swz / nwgx) << 7, n0 = (swz % nwgx) << 6;
    int wm = (wid & 1) << 6, wn = (wid >> 1) << 5;

    int rIn = lane >> 3;
    int cSw = (((lane & 7) ^ (lane >> 3)) << 3);
    int sA = wid << 2;
    int sB = wid << 1;
    int fr = lane & 15;
    int ksw0 = (((lane >> 4) ^ (lane & 7)) << 3);
    int ksw1 = (((4 + (lane >> 4)) ^ (lane & 7)) << 3);

    f32x4 acc[4][2];
    #pragma unroll
    for (int i = 0; i < 4; i++)
        #pragma unroll
        for (int j = 0; j < 2; j++)
            acc[i][j] = (f32x4){0.f, 0.f, 0.f, 0.f};

    // prologue: stage K-tile 0 into buf 0
    #pragma unroll
    for (int t = 0; t < 4; t++) {
        int s = sA + t;
        gload_lds16(A + (size_t)(m0 + (s << 3) + rIn) * K + cSw, As + (s << 9));
    }
    #pragma unroll
    for (int t = 0; t < 2; t++) {
        int s = sB + t;
        gload_lds16(W + (size_t)(n0 + (s << 3) + rIn) * K + cSw, Bs + (s << 9));
    }
    __syncthreads();

    int nk = K >> 6;
    for (int kt = 0; kt < nk; kt++) {
        int buf = kt & 1;
        const u16* Ab = As + (buf << 13);
        const u16* Bb = Bs + (buf << 12);
        if (kt + 1 < nk) {
            int k0 = (kt + 1) << 6;
            int boA = (buf ^ 1) << 13;
            int boB = (buf ^ 1) << 12;
            #pragma unroll
            for (int t = 0; t < 4; t++) {
                int s = sA + t;
                gload_lds16(A + (size_t)(m0 + (s << 3) + rIn) * K + k0 + cSw, As + boA + (s << 9));
            }
            #pragma unroll
            for (int t = 0; t < 2; t++) {
                int s = sB + t;
                gload_lds16(W + (size_t)(n0 + (s << 3) + rIn) * K + k0 + cSw, Bs + boB + (s << 9));
            }
        }
        #pragma unroll
        for (int ch = 0; ch < 2; ch++) {
            int ks = ch ? ksw1 : ksw0;
            short8 af[4], bf[2];
            #pragma unroll
            for (int mi = 0; mi < 4; mi++)
                af[mi] = *(const short8*)(Ab + (size_t)(wm + (mi << 4) + fr) * 64 + ks);
            #pragma unroll
            for (int ni = 0; ni < 2; ni++)
                bf[ni] = *(const short8*)(Bb + (size_t)(wn + (ni << 4) + fr) * 64 + ks);
            #pragma unroll
            for (int mi = 0; mi < 4; mi++)
                #pragma unroll
                for (int ni = 0; ni < 2; ni++)
                    acc[mi][ni] = __builtin_amdgcn_mfma_f32_16x16x32_bf16(
                        af[mi], bf[ni], acc[mi][ni], 0, 0, 0);
        }
        __syncthreads();
    }

    int erow = (lane >> 4) << 2;
    #pragma unroll
    for (int ni = 0; ni < 2; ni++) {
        int col = n0 + wn + (ni << 4) + fr;
        float bv = bias[col];
        #pragma unroll
        for (int mi = 0; mi < 4; mi++) {
            #pragma unroll
            for (int r = 0; r < 4; r++) {
                int row = m0 + wm + (mi << 4) + erow + r;
                float val = acc[mi][ni][r] + bv;
                if (GELU)  val = 0.5f * val * (1.0f + erff(val * 0.70710678118654752f));
                if (RESID) val += resid[(size_t)row * N + col];
                if (OUTBF) ((u16*)Cout)[(size_t)row * N + col] = f2b(val);
                else       ((float*)Cout)[(size_t)row * N + col] = val;
            }
        }
    }
}

// --- MFMA flash attention v7: swapped QK^T + permlane-swap in-reg softmax ---
__global__ __launch_bounds__(256) void fattn_mfma(const u16* __restrict__ QKV,
                                                  const u16* __restrict__ VT,
                                                  u16* __restrict__ O) {
    __shared__ __attribute__((aligned(16))) u16 QP[4096];        // Q tile
    __shared__ __attribute__((aligned(16))) u16 Ks[2][4096];     // dbuf [2ch][64][32]
    __shared__ __attribute__((aligned(16))) u16 Vt[2][4096];     // dbuf [2ch][64d][32k]
    const int ld = 3 * DM;
    int bid = ((blockIdx.x & 7) << 7) + (blockIdx.x >> 3);   // 1024 blocks, cpx=128
    int qt = bid & 31, bh = bid >> 5;
    int h = bh & (NHEADS - 1), b = bh >> 4;
    int tid = threadIdx.x, wid = tid >> 6, lane = tid & 63;
    int fr = lane & 15;
    int fcs = (((lane >> 4) ^ ((fr >> 1) & 3)) << 3);
    int lsw = (((lane & 3) ^ ((lane >> 3) & 3)) << 3);
    size_t tokb = (size_t)b * SQ;
    const u16* Qg  = QKV + tokb * ld + h * HD;
    const u16* Kg  = QKV + tokb * ld + DM + h * HD;
    const u16* VTg = VT + ((size_t)bh * HD) * SQ;   // [d][tok]
    int s0 = wid << 1;

    {   // stage Q tile
        #pragma unroll
        for (int t = 0; t < 2; t++) {
            int s = s0 + t;
            const u16* g = Qg + (size_t)(qt * 64 + ((s & 3) << 4) + (lane >> 2)) * ld
                         + ((s >> 2) << 5) + lsw;
            gload_lds16(g, QP + (s << 9));
        }
    }
    {   // stage K/V tile 0 into buf 0
        #pragma unroll
        for (int t = 0; t < 2; t++) {
            int s = s0 + t;
            const u16* g = Kg + (size_t)(((s & 3) << 4) + (lane >> 2)) * ld
                         + ((s >> 2) << 5) + lsw;
            gload_lds16(g, Ks[0] + (s << 9));
            const u16* gv = VTg + (size_t)(((s & 3) << 4) + (lane >> 2)) * SQ
                          + ((s >> 2) << 5) + lsw;
            gload_lds16(gv, Vt[0] + (s << 9));
        }
    }
    f32x4 oacc[4];
    #pragma unroll
    for (int di = 0; di < 4; di++) oacc[di] = (f32x4){0.f, 0.f, 0.f, 0.f};
    float lsum = 0.f;
    __syncthreads();   // Q + tile0 visible
    short8 aq0 = *(const short8*)(QP + ((wid << 4) + fr) * 32 + fcs);
    short8 aq1 = *(const short8*)(QP + 2048 + ((wid << 4) + fr) * 32 + fcs);

    for (int kt = 0; kt < SQ / 64; kt++) {
        int buf = kt & 1;
        if (kt + 1 < SQ / 64) {   // prefetch next K/V tile into buf^1
            #pragma unroll
            for (int t = 0; t < 2; t++) {
                int s = s0 + t;
                const u16* g = Kg + (size_t)((kt + 1) * 64 + ((s & 3) << 4) + (lane >> 2)) * ld
                             + ((s >> 2) << 5) + lsw;
                gload_lds16(g, Ks[buf ^ 1] + (s << 9));
                const u16* gv = VTg + (size_t)(((s & 3) << 4) + (lane >> 2)) * SQ
                              + (kt + 1) * 64 + ((s >> 2) << 5) + lsw;
                gload_lds16(gv, Vt[buf ^ 1] + (s << 9));
            }
        }
        // S^T = K Q^T: lane holds P[q=fr][k = ni*16 + hi*4 + r]
        float p[4][4];
        #pragma unroll
        for (int ni = 0; ni < 4; ni++) {
            short8 bk0 = *(const short8*)(Ks[buf] + ((ni << 4) + fr) * 32 + fcs);
            short8 bk1 = *(const short8*)(Ks[buf] + 2048 + ((ni << 4) + fr) * 32 + fcs);
            f32x4 z = (f32x4){0.f, 0.f, 0.f, 0.f};
            __builtin_amdgcn_s_setprio(1);
            z = __builtin_amdgcn_mfma_f32_16x16x32_bf16(bk0, aq0, z, 0, 0, 0);
            z = __builtin_amdgcn_mfma_f32_16x16x32_bf16(bk1, aq1, z, 0, 0, 0);
            __builtin_amdgcn_s_setprio(0);
            #pragma unroll
            for (int r = 0; r < 4; r++) {
                float e = __expf(z[r]);
                lsum += e;
                p[ni][r] = e;
            }
        }
        unsigned int W[4][2];
        #pragma unroll
        for (int ni = 0; ni < 4; ni++) {
            asm("v_cvt_pk_bf16_f32 %0, %1, %2" : "=v"(W[ni][0]) : "v"(p[ni][0]), "v"(p[ni][1]));
            asm("v_cvt_pk_bf16_f32 %0, %1, %2" : "=v"(W[ni][1]) : "v"(p[ni][2]), "v"(p[ni][3]));
        }
        union { unsigned int w[4]; short8 v; } fA0, fA1;
        #pragma unroll
        for (int w = 0; w < 2; w++) {
            unsigned int a0 = W[0][w], b0 = W[1][w];
            asm("v_permlane32_swap_b32 %0, %1" : "+v"(a0), "+v"(b0));
            asm("v_permlane16_swap_b32 %0, %1" : "+v"(a0), "+v"(b0));
            fA0.w[w] = a0; fA0.w[w + 2] = b0;
            unsigned int a1 = W[2][w], b1 = W[3][w];
            asm("v_permlane32_swap_b32 %0, %1" : "+v"(a1), "+v"(b1));
            asm("v_permlane16_swap_b32 %0, %1" : "+v"(a1), "+v"(b1));
            fA1.w[w] = a1; fA1.w[w + 2] = b1;
        }
        short8 ap0 = fA0.v, ap1 = fA1.v;
        __builtin_amdgcn_s_setprio(1);
        #pragma unroll
        for (int di = 0; di < 4; di++) {
            short8 bv0 = *(const short8*)(Vt[buf] + ((di << 4) + fr) * 32 + fcs);
            short8 bv1 = *(const short8*)(Vt[buf] + 2048 + ((di << 4) + fr) * 32 + fcs);
            oacc[di] = __builtin_amdgcn_mfma_f32_16x16x32_bf16(ap0, bv0, oacc[di], 0, 0, 0);
            oacc[di] = __builtin_amdgcn_mfma_f32_16x16x32_bf16(ap1, bv1, oacc[di], 0, 0, 0);
        }
        __builtin_amdgcn_s_setprio(0);
        __syncthreads();   // drain prefetch; protect buf swap
    }
    lsum += __shfl_xor(lsum, 16, 64);
    lsum += __shfl_xor(lsum, 32, 64);
    float inv = 1.0f / lsum;           // valid for q = fr
    float invq[4];
    #pragma unroll
    for (int r = 0; r < 4; r++)
        invq[r] = __shfl(inv, ((lane >> 4) << 2) + r, 64);   // inv for q = hi*4+r
    #pragma unroll
    for (int di = 0; di < 4; di++) {
        int d = (di << 4) + fr;
        #pragma unroll
        for (int r = 0; r < 4; r++) {
            int q = qt * 64 + (wid << 4) + ((lane >> 4) << 2) + r;
            O[(tokb + q) * DM + h * HD + d] = f2b(oacc[di][r] * invq[r]);
        }
    }
}

extern "C" void kernel_launch(void* const* d_in, const int* in_sizes, int n_in,
                              void* d_out, int out_size, void* d_ws, size_t ws_size,
                              hipStream_t stream) {
    if (n_in < 17) return;
    const float* x   = (const float*)d_in[0];
    const float* wq  = (const float*)d_in[1];
    const float* bq  = (const float*)d_in[2];
    const float* wk  = (const float*)d_in[3];
    const float* bk  = (const float*)d_in[4];
    const float* wv  = (const float*)d_in[5];
    const float* bv  = (const float*)d_in[6];
    const float* wo  = (const float*)d_in[7];
    const float* bo  = (const float*)d_in[8];
    const float* g1  = (const float*)d_in[9];
    const float* e1  = (const float*)d_in[10];
    const float* w1  = (const float*)d_in[11];
    const float* b1  = (const float*)d_in[12];
    const float* w2  = (const float*)d_in[13];
    const float* b2  = (const float*)d_in[14];
    const float* g2  = (const float*)d_in[15];
    const float* e2  = (const float*)d_in[16];

    float* F = (float*)d_ws;
    size_t off = 0;
    float* xnf   = F + off; off += NX;
    u16*   xnb   = (u16*)(F + off); off += NX / 2;
    u16*   qkvb  = (u16*)(F + off); off += (size_t)NTOK * 3 * DM / 2;
    u16*   vTb   = (u16*)(F + off); off += (size_t)NTOK * DM / 2;   // vT[bh][d][tok]
    float* y     = F + off; off += NX;
    u16*   aob   = (u16*)(F + off); off += NX / 2;
    u16*   hb    = (u16*)(F + off); off += (size_t)NTOK * HM / 2;
    u16*   wqkvb = (u16*)(F + off); off += (size_t)3 * DM * DM / 2;
    u16*   wob   = (u16*)(F + off); off += (size_t)DM * DM / 2;
    u16*   w1b   = (u16*)(F + off); off += (size_t)HM * DM / 2;
    u16*   w2b   = (u16*)(F + off); off += (size_t)DM * HM / 2;
    float* bqkv  = F + off; off += 3 * DM;
    if (ws_size < off * sizeof(float)) return;

    dim3 blk(256);
    cvt_all<<<(12 * DM * DM / 4 + 3 * DM + 255) / 256, blk, 0, stream>>>(
        wq, wk, wv, wo, w1, w2, bq, bk, bv, bqkv, wqkvb);

    // xn1 = LN1(x)
    ln_kernel<<<NTOK, blk, 0, stream>>>(x, g1, e1, xnf, xnb);
    // qkv = xn1 @ [0.125wq|wk|wv]^T + b   (bf16 out)
    gemm_bt<0,0,1><<<dim3(3 * DM / 128, NTOK / 128), blk, 0, stream>>>(
        xnb, wqkvb, bqkv, nullptr, qkvb, NTOK, 3 * DM, DM);
    // vT = transpose(V region)
    vtr_kernel<<<NBATCH * NHEADS * (SQ / 64), blk, 0, stream>>>(qkvb, vTb);
    // aob = softmax(q k^T) v
    fattn_mfma<<<NBATCH * NHEADS * (SQ / 64), blk, 0, stream>>>(qkvb, vTb, aob);
    // y = xn1 + aob @ wo^T + bo
    gemm_n64<0,1,0><<<dim3(DM / 64, NTOK / 128), blk, 0, stream>>>(
        aob, wob, bo, xnf, y, NTOK, DM, DM);
    // xn2 = LN2(y)
    ln_kernel<<<NTOK, blk, 0, stream>>>(y, g2, e2, xnf, xnb);
    // hb = gelu(xn2 @ w1^T + b1)   (bf16 out)
    gemm_bt<1,0,1><<<dim3(HM / 128, NTOK / 128), blk, 0, stream>>>(
        xnb, w1b, b1, nullptr, hb, NTOK, HM, DM);
    // out = xn2 + hb @ w2^T + b2   (fp32 out)
    gemm_n64<0,1,0><<<dim3(DM / 64, NTOK / 128), blk, 0, stream>>>(
        hb, w2b, b2, xnf, d_out, NTOK, DM, HM);
}

// Round 10
// 368.942 us; speedup vs baseline: 1.0610x; 1.0610x over previous
//
#include <hip/hip_runtime.h>
#include <hip/hip_bf16.h>

typedef unsigned short u16;
typedef __attribute__((ext_vector_type(8))) short short8;   // 8 bf16 (4 VGPRs)
typedef __attribute__((ext_vector_type(4))) float f32x4;    // 4 fp32 acc

#define DM 1024      // d_model
#define HM 4096      // ffn hidden
#define NHEADS 16
#define HD 64        // head dim
#define SQ 2048      // seq len
#define NBATCH 2
#define NTOK 4096    // NBATCH*SQ

#define NX  ((size_t)NTOK * DM)

__device__ __forceinline__ u16 f2b(float f) {   // fp32 -> bf16 RNE
    union { float f; unsigned int i; } w; w.f = f;
    unsigned int x = w.i;
    return (u16)((x + 0x7FFFu + ((x >> 16) & 1u)) >> 16);
}

__device__ __forceinline__ void gload_lds16(const void* g, void* l) {
    __builtin_amdgcn_global_load_lds(
        (const __attribute__((address_space(1))) void*)g,
        (__attribute__((address_space(3))) void*)l, 16, 0, 0);
}

// ---- all weights fp32 -> bf16 + bias pack, ONE kernel ----
// dst layout (u16): wq|wk|wv (3M) | wo (1M) | w1 (4M) | w2 (4M)
// wq/bq carry 0.125*log2(e): S arrives pre-scaled for exp2 (v_exp_f32).
__global__ void cvt_all(const float* __restrict__ wq, const float* __restrict__ wk,
                        const float* __restrict__ wv, const float* __restrict__ wo,
                        const float* __restrict__ w1, const float* __restrict__ w2,
                        const float* __restrict__ bq, const float* __restrict__ bk,
                        const float* __restrict__ bv, float* __restrict__ bias_dst,
                        u16* __restrict__ dst) {
    const int NW4 = DM * DM / 4;   // float4s per DMxDM matrix
    const float QS = 0.18033688011112042f;   // 0.125 * log2(e)
    int i = blockIdx.x * 256 + threadIdx.x;
    if (i < 12 * NW4) {
        const float* src; int base; float sc = 1.0f;
        if      (i <     NW4) { src = wq; base = 0;       sc = QS; }
        else if (i < 2 * NW4) { src = wk; base = NW4; }
        else if (i < 3 * NW4) { src = wv; base = 2 * NW4; }
        else if (i < 4 * NW4) { src = wo; base = 3 * NW4; }
        else if (i < 8 * NW4) { src = w1; base = 4 * NW4; }
        else                  { src = w2; base = 8 * NW4; }
        float4 f = ((const float4*)src)[i - base];
        ushort4 o;
        o.x = f2b(f.x * sc); o.y = f2b(f.y * sc);
        o.z = f2b(f.z * sc); o.w = f2b(f.w * sc);
        ((ushort4*)dst)[i] = o;
    } else {
        int j = i - 12 * NW4;
        if (j < 3 * DM) {
            float v = (j < DM) ? bq[j] * QS
                    : (j < 2 * DM) ? bk[j - DM] : bv[j - 2 * DM];
            bias_dst[j] = v;
        }
    }
}

// ---------------- LayerNorm: fp32 in, fp32 + bf16 out ----------------
__global__ void ln_kernel(const float* __restrict__ xin, const float* __restrict__ g,
                          const float* __restrict__ b, float* __restrict__ outf,
                          u16* __restrict__ outb) {
    int t = blockIdx.x, tid = threadIdx.x;
    float4 f = ((const float4*)(xin + (size_t)t * DM))[tid];
    float v0 = f.x, v1 = f.y, v2 = f.z, v3 = f.w;
    float s  = v0 + v1 + v2 + v3;
    float ss = v0*v0 + v1*v1 + v2*v2 + v3*v3;
    #pragma unroll
    for (int o = 32; o > 0; o >>= 1) {
        s  += __shfl_down(s,  o, 64);
        ss += __shfl_down(ss, o, 64);
    }
    __shared__ float rs[4], rss[4];
    int w = tid >> 6, lane = tid & 63;
    if (!lane) { rs[w] = s; rss[w] = ss; }
    __syncthreads();
    s  = rs[0] + rs[1] + rs[2] + rs[3];
    ss = rss[0] + rss[1] + rss[2] + rss[3];
    float mean = s * (1.0f / DM);
    float var  = ss * (1.0f / DM) - mean * mean;
    float rstd = rsqrtf(var + 1e-5f);
    float4 gu = ((const float4*)g)[tid];
    float4 bu = ((const float4*)b)[tid];
    float4 o;
    o.x = (v0 - mean) * rstd * gu.x + bu.x;
    o.y = (v1 - mean) * rstd * gu.y + bu.y;
    o.z = (v2 - mean) * rstd * gu.z + bu.z;
    o.w = (v3 - mean) * rstd * gu.w + bu.w;
    ((float4*)(outf + (size_t)t * DM))[tid] = o;
    ushort4 ob; ob.x = f2b(o.x); ob.y = f2b(o.y); ob.z = f2b(o.z); ob.w = f2b(o.w);
    ((ushort4*)(outb + (size_t)t * DM))[tid] = ob;
}

// ---- V transpose: qkv V-region [tok][h*64+d] -> vT[b*16+h][d][tok_in_batch] ----
__global__ void vtr_kernel(const u16* __restrict__ qkv, u16* __restrict__ vT) {
    __shared__ u16 tile[64][72];
    int bid = blockIdx.x;          // 32 bh x 32 t-tiles
    int tt = bid & 31, bh = bid >> 5;
    int h = bh & (NHEADS - 1), b = bh >> 4;
    int tid = threadIdx.x;
    int r = tid >> 2, c0 = (tid & 3) << 4;
    const u16* src = qkv + ((size_t)(b * SQ + tt * 64 + r)) * (3 * DM) + 2 * DM + h * HD + c0;
    #pragma unroll
    for (int j = 0; j < 4; j++)
        *(ushort4*)&tile[r][c0 + (j << 2)] = *(const ushort4*)(src + (j << 2));
    __syncthreads();
    int dd = tid >> 2, t0 = (tid & 3) << 4;
    u16* dst = vT + ((size_t)bh * HD + dd) * SQ + tt * 64 + t0;
    #pragma unroll
    for (int j = 0; j < 4; j++) {
        ushort4 v;
        v.x = tile[t0 + (j << 2) + 0][dd];
        v.y = tile[t0 + (j << 2) + 1][dd];
        v.z = tile[t0 + (j << 2) + 2][dd];
        v.w = tile[t0 + (j << 2) + 3][dd];
        *(ushort4*)(dst + (j << 2)) = v;
    }
}

// ------- MFMA GEMM 128x128, BK=64, dbuf + 8-way XOR chunk swizzle -------
// (R8 form — the T4 half-tile ring regressed total time in R9; reverted.)
template<int GELU, int RESID, int OUTBF>
__global__ __launch_bounds__(256, 2)
void gemm_bt(const u16* __restrict__ A, const u16* __restrict__ W,
             const float* __restrict__ bias, const float* __restrict__ resid,
             void* __restrict__ Cout, int M, int N, int K) {
    __shared__ __attribute__((aligned(16))) u16 As[2 * 128 * 64];   // 32 KB
    __shared__ __attribute__((aligned(16))) u16 Bs[2 * 128 * 64];   // 32 KB
    int tid  = threadIdx.x;
    int wid  = tid >> 6, lane = tid & 63;
    int m0 = blockIdx.y << 7, n0 = blockIdx.x << 7;
    int wm = (wid & 1) << 6, wn = (wid >> 1) << 6;

    int rIn = lane >> 3;
    int cSw = (((lane & 7) ^ (lane >> 3)) << 3);          // swizzled source chunk
    int s0  = wid << 2;
    int fr = lane & 15;
    int ksw0 = (((lane >> 4) ^ (lane & 7)) << 3);         // ch=0 swizzled k-off
    int ksw1 = (((4 + (lane >> 4)) ^ (lane & 7)) << 3);   // ch=1

    f32x4 acc[4][4];
    #pragma unroll
    for (int i = 0; i < 4; i++)
        #pragma unroll
        for (int j = 0; j < 4; j++)
            acc[i][j] = (f32x4){0.f, 0.f, 0.f, 0.f};

    // prologue: stage K-tile 0 into buf 0
    #pragma unroll
    for (int t = 0; t < 4; t++) {
        int s = s0 + t;
        gload_lds16(A + (size_t)(m0 + (s << 3) + rIn) * K + cSw, As + (s << 9));
        gload_lds16(W + (size_t)(n0 + (s << 3) + rIn) * K + cSw, Bs + (s << 9));
    }
    __syncthreads();

    int nk = K >> 6;
    for (int kt = 0; kt < nk; kt++) {
        int buf = kt & 1;
        const u16* Ab = As + (buf << 13);
        const u16* Bb = Bs + (buf << 13);
        if (kt + 1 < nk) {              // prefetch next tile into other buffer
            int k0 = (kt + 1) << 6;
            int bo = (buf ^ 1) << 13;
            #pragma unroll
            for (int t = 0; t < 4; t++) {
                int s = s0 + t;
                gload_lds16(A + (size_t)(m0 + (s << 3) + rIn) * K + k0 + cSw, As + bo + (s << 9));
                gload_lds16(W + (size_t)(n0 + (s << 3) + rIn) * K + k0 + cSw, Bs + bo + (s << 9));
            }
        }
        #pragma unroll
        for (int ch = 0; ch < 2; ch++) {
            int ks = ch ? ksw1 : ksw0;
            short8 af[4], bf[4];
            #pragma unroll
            for (int mi = 0; mi < 4; mi++)
                af[mi] = *(const short8*)(Ab + (size_t)(wm + (mi << 4) + fr) * 64 + ks);
            #pragma unroll
            for (int ni = 0; ni < 4; ni++)
                bf[ni] = *(const short8*)(Bb + (size_t)(wn + (ni << 4) + fr) * 64 + ks);
            #pragma unroll
            for (int mi = 0; mi < 4; mi++)
                #pragma unroll
                for (int ni = 0; ni < 4; ni++)
                    acc[mi][ni] = __builtin_amdgcn_mfma_f32_16x16x32_bf16(
                        af[mi], bf[ni], acc[mi][ni], 0, 0, 0);
        }
        __syncthreads();   // prefetch drained (compiler vmcnt) + buf reads done
    }

    int erow = (lane >> 4) << 2;
    #pragma unroll
    for (int ni = 0; ni < 4; ni++) {
        int col = n0 + wn + (ni << 4) + fr;
        float bv = bias[col];
        #pragma unroll
        for (int mi = 0; mi < 4; mi++) {
            #pragma unroll
            for (int r = 0; r < 4; r++) {
                int row = m0 + wm + (mi << 4) + erow + r;
                float val = acc[mi][ni][r] + bv;
                if (GELU)  val = 0.5f * val * (1.0f + erff(val * 0.70710678118654752f));
                if (RESID) val += resid[(size_t)row * N + col];
                if (OUTBF) ((u16*)Cout)[(size_t)row * N + col] = f2b(val);
                else       ((float*)Cout)[(size_t)row * N + col] = val;
            }
        }
    }
}

// ------- MFMA GEMM 128x64, BK=64, dbuf + 8-way XOR chunk swizzle -------
// XCD swizzle kept: B-operand (<=2 MB) is L2-resident per XCD.
template<int GELU, int RESID, int OUTBF>
__global__ __launch_bounds__(256, 3)
void gemm_n64(const u16* __restrict__ A, const u16* __restrict__ W,
              const float* __restrict__ bias, const float* __restrict__ resid,
              void* __restrict__ Cout, int M, int N, int K) {
    __shared__ __attribute__((aligned(16))) u16 As[2 * 128 * 64];   // 32 KB
    __shared__ __attribute__((aligned(16))) u16 Bs[2 * 64 * 64];    // 16 KB
    int tid  = threadIdx.x;
    int wid  = tid >> 6, lane = tid & 63;
    int nwgx = gridDim.x;
    int bidl = blockIdx.y * nwgx + blockIdx.x;
    int cpx  = (nwgx * gridDim.y) >> 3;
    int swz  = (bidl & 7) * cpx + (bidl >> 3);
    int m0 = (swz / nwgx) << 7, n0 = (swz % nwgx) << 6;
    int wm = (wid & 1) << 6, wn = (wid >> 1) << 5;

    int rIn = lane >> 3;
    int cSw = (((lane & 7) ^ (lane >> 3)) << 3);
    int sA = wid << 2;
    int sB = wid << 1;
    int fr = lane & 15;
    int ksw0 = (((lane >> 4) ^ (lane & 7)) << 3);
    int ksw1 = (((4 + (lane >> 4)) ^ (lane & 7)) << 3);

    f32x4 acc[4][2];
    #pragma unroll
    for (int i = 0; i < 4; i++)
        #pragma unroll
        for (int j = 0; j < 2; j++)
            acc[i][j] = (f32x4){0.f, 0.f, 0.f, 0.f};

    // prologue: stage K-tile 0 into buf 0
    #pragma unroll
    for (int t = 0; t < 4; t++) {
        int s = sA + t;
        gload_lds16(A + (size_t)(m0 + (s << 3) + rIn) * K + cSw, As + (s << 9));
    }
    #pragma unroll
    for (int t = 0; t < 2; t++) {
        int s = sB + t;
        gload_lds16(W + (size_t)(n0 + (s << 3) + rIn) * K + cSw, Bs + (s << 9));
    }
    __syncthreads();

    int nk = K >> 6;
    for (int kt = 0; kt < nk; kt++) {
        int buf = kt & 1;
        const u16* Ab = As + (buf << 13);
        const u16* Bb = Bs + (buf << 12);
        if (kt + 1 < nk) {
            int k0 = (kt + 1) << 6;
            int boA = (buf ^ 1) << 13;
            int boB = (buf ^ 1) << 12;
            #pragma unroll
            for (int t = 0; t < 4; t++) {
                int s = sA + t;
                gload_lds16(A + (size_t)(m0 + (s << 3) + rIn) * K + k0 + cSw, As + boA + (s << 9));
            }
            #pragma unroll
            for (int t = 0; t < 2; t++) {
                int s = sB + t;
                gload_lds16(W + (size_t)(n0 + (s << 3) + rIn) * K + k0 + cSw, Bs + boB + (s << 9));
            }
        }
        #pragma unroll
        for (int ch = 0; ch < 2; ch++) {
            int ks = ch ? ksw1 : ksw0;
            short8 af[4], bf[2];
            #pragma unroll
            for (int mi = 0; mi < 4; mi++)
                af[mi] = *(const short8*)(Ab + (size_t)(wm + (mi << 4) + fr) * 64 + ks);
            #pragma unroll
            for (int ni = 0; ni < 2; ni++)
                bf[ni] = *(const short8*)(Bb + (size_t)(wn + (ni << 4) + fr) * 64 + ks);
            #pragma unroll
            for (int mi = 0; mi < 4; mi++)
                #pragma unroll
                for (int ni = 0; ni < 2; ni++)
                    acc[mi][ni] = __builtin_amdgcn_mfma_f32_16x16x32_bf16(
                        af[mi], bf[ni], acc[mi][ni], 0, 0, 0);
        }
        __syncthreads();
    }

    int erow = (lane >> 4) << 2;
    #pragma unroll
    for (int ni = 0; ni < 2; ni++) {
        int col = n0 + wn + (ni << 4) + fr;
        float bv = bias[col];
        #pragma unroll
        for (int mi = 0; mi < 4; mi++) {
            #pragma unroll
            for (int r = 0; r < 4; r++) {
                int row = m0 + wm + (mi << 4) + erow + r;
                float val = acc[mi][ni][r] + bv;
                if (GELU)  val = 0.5f * val * (1.0f + erff(val * 0.70710678118654752f));
                if (RESID) val += resid[(size_t)row * N + col];
                if (OUTBF) ((u16*)Cout)[(size_t)row * N + col] = f2b(val);
                else       ((float*)Cout)[(size_t)row * N + col] = val;
            }
        }
    }
}

// --- MFMA flash attention v8: swapped QK^T + permlane softmax + direct exp2 ---
// Q pre-scaled by log2(e) at cvt time -> P = 2^S via single v_exp_f32 (no mul).
__global__ __launch_bounds__(256) void fattn_mfma(const u16* __restrict__ QKV,
                                                  const u16* __restrict__ VT,
                                                  u16* __restrict__ O) {
    __shared__ __attribute__((aligned(16))) u16 QP[4096];        // Q tile
    __shared__ __attribute__((aligned(16))) u16 Ks[2][4096];     // dbuf [2ch][64][32]
    __shared__ __attribute__((aligned(16))) u16 Vt[2][4096];     // dbuf [2ch][64d][32k]
    const int ld = 3 * DM;
    int bid = ((blockIdx.x & 7) << 7) + (blockIdx.x >> 3);   // 1024 blocks, cpx=128
    int qt = bid & 31, bh = bid >> 5;
    int h = bh & (NHEADS - 1), b = bh >> 4;
    int tid = threadIdx.x, wid = tid >> 6, lane = tid & 63;
    int fr = lane & 15;
    int fcs = (((lane >> 4) ^ ((fr >> 1) & 3)) << 3);
    int lsw = (((lane & 3) ^ ((lane >> 3) & 3)) << 3);
    size_t tokb = (size_t)b * SQ;
    const u16* Qg  = QKV + tokb * ld + h * HD;
    const u16* Kg  = QKV + tokb * ld + DM + h * HD;
    const u16* VTg = VT + ((size_t)bh * HD) * SQ;   // [d][tok]
    int s0 = wid << 1;

    {   // stage Q tile
        #pragma unroll
        for (int t = 0; t < 2; t++) {
            int s = s0 + t;
            const u16* g = Qg + (size_t)(qt * 64 + ((s & 3) << 4) + (lane >> 2)) * ld
                         + ((s >> 2) << 5) + lsw;
            gload_lds16(g, QP + (s << 9));
        }
    }
    {   // stage K/V tile 0 into buf 0
        #pragma unroll
        for (int t = 0; t < 2; t++) {
            int s = s0 + t;
            const u16* g = Kg + (size_t)(((s & 3) << 4) + (lane >> 2)) * ld
                         + ((s >> 2) << 5) + lsw;
            gload_lds16(g, Ks[0] + (s << 9));
            const u16* gv = VTg + (size_t)(((s & 3) << 4) + (lane >> 2)) * SQ
                          + ((s >> 2) << 5) + lsw;
            gload_lds16(gv, Vt[0] + (s << 9));
        }
    }
    f32x4 oacc[4];
    #pragma unroll
    for (int di = 0; di < 4; di++) oacc[di] = (f32x4){0.f, 0.f, 0.f, 0.f};
    float lsum = 0.f;
    __syncthreads();   // Q + tile0 visible
    short8 aq0 = *(const short8*)(QP + ((wid << 4) + fr) * 32 + fcs);
    short8 aq1 = *(const short8*)(QP + 2048 + ((wid << 4) + fr) * 32 + fcs);

    for (int kt = 0; kt < SQ / 64; kt++) {
        int buf = kt & 1;
        if (kt + 1 < SQ / 64) {   // prefetch next K/V tile into buf^1
            #pragma unroll
            for (int t = 0; t < 2; t++) {
                int s = s0 + t;
                const u16* g = Kg + (size_t)((kt + 1) * 64 + ((s & 3) << 4) + (lane >> 2)) * ld
                             + ((s >> 2) << 5) + lsw;
                gload_lds16(g, Ks[buf ^ 1] + (s << 9));
                const u16* gv = VTg + (size_t)(((s & 3) << 4) + (lane >> 2)) * SQ
                              + (kt + 1) * 64 + ((s >> 2) << 5) + lsw;
                gload_lds16(gv, Vt[buf ^ 1] + (s << 9));
            }
        }
        // S^T = K Q^T: lane holds P[q=fr][k = ni*16 + hi*4 + r]; S pre-scaled by log2e
        float p[4][4];
        #pragma unroll
        for (int ni = 0; ni < 4; ni++) {
            short8 bk0 = *(const short8*)(Ks[buf] + ((ni << 4) + fr) * 32 + fcs);
            short8 bk1 = *(const short8*)(Ks[buf] + 2048 + ((ni << 4) + fr) * 32 + fcs);
            f32x4 z = (f32x4){0.f, 0.f, 0.f, 0.f};
            __builtin_amdgcn_s_setprio(1);
            z = __builtin_amdgcn_mfma_f32_16x16x32_bf16(bk0, aq0, z, 0, 0, 0);
            z = __builtin_amdgcn_mfma_f32_16x16x32_bf16(bk1, aq1, z, 0, 0, 0);
            __builtin_amdgcn_s_setprio(0);
            #pragma unroll
            for (int r = 0; r < 4; r++) {
                float e;
                asm("v_exp_f32 %0, %1" : "=v"(e) : "v"(z[r]));   // 2^S = e^(S/log2e)
                lsum += e;
                p[ni][r] = e;
            }
        }
        unsigned int W[4][2];
        #pragma unroll
        for (int ni = 0; ni < 4; ni++) {
            asm("v_cvt_pk_bf16_f32 %0, %1, %2" : "=v"(W[ni][0]) : "v"(p[ni][0]), "v"(p[ni][1]));
            asm("v_cvt_pk_bf16_f32 %0, %1, %2" : "=v"(W[ni][1]) : "v"(p[ni][2]), "v"(p[ni][3]));
        }
        union { unsigned int w[4]; short8 v; } fA0, fA1;
        #pragma unroll
        for (int w = 0; w < 2; w++) {
            unsigned int a0 = W[0][w], b0 = W[1][w];
            asm("v_permlane32_swap_b32 %0, %1" : "+v"(a0), "+v"(b0));
            asm("v_permlane16_swap_b32 %0, %1" : "+v"(a0), "+v"(b0));
            fA0.w[w] = a0; fA0.w[w + 2] = b0;
            unsigned int a1 = W[2][w], b1 = W[3][w];
            asm("v_permlane32_swap_b32 %0, %1" : "+v"(a1), "+v"(b1));
            asm("v_permlane16_swap_b32 %0, %1" : "+v"(a1), "+v"(b1));
            fA1.w[w] = a1; fA1.w[w + 2] = b1;
        }
        short8 ap0 = fA0.v, ap1 = fA1.v;
        __builtin_amdgcn_s_setprio(1);
        #pragma unroll
        for (int di = 0; di < 4; di++) {
            short8 bv0 = *(const short8*)(Vt[buf] + ((di << 4) + fr) * 32 + fcs);
            short8 bv1 = *(const short8*)(Vt[buf] + 2048 + ((di << 4) + fr) * 32 + fcs);
            oacc[di] = __builtin_amdgcn_mfma_f32_16x16x32_bf16(ap0, bv0, oacc[di], 0, 0, 0);
            oacc[di] = __builtin_amdgcn_mfma_f32_16x16x32_bf16(ap1, bv1, oacc[di], 0, 0, 0);
        }
        __builtin_amdgcn_s_setprio(0);
        __syncthreads();   // drain prefetch; protect buf swap
    }
    lsum += __shfl_xor(lsum, 16, 64);
    lsum += __shfl_xor(lsum, 32, 64);
    float inv = 1.0f / lsum;           // valid for q = fr
    float invq[4];
    #pragma unroll
    for (int r = 0; r < 4; r++)
        invq[r] = __shfl(inv, ((lane >> 4) << 2) + r, 64);   // inv for q = hi*4+r
    #pragma unroll
    for (int di = 0; di < 4; di++) {
        int d = (di << 4) + fr;
        #pragma unroll
        for (int r = 0; r < 4; r++) {
            int q = qt * 64 + (wid << 4) + ((lane >> 4) << 2) + r;
            O[(tokb + q) * DM + h * HD + d] = f2b(oacc[di][r] * invq[r]);
        }
    }
}

extern "C" void kernel_launch(void* const* d_in, const int* in_sizes, int n_in,
                              void* d_out, int out_size, void* d_ws, size_t ws_size,
                              hipStream_t stream) {
    if (n_in < 17) return;
    const float* x   = (const float*)d_in[0];
    const float* wq  = (const float*)d_in[1];
    const float* bq  = (const float*)d_in[2];
    const float* wk  = (const float*)d_in[3];
    const float* bk  = (const float*)d_in[4];
    const float* wv  = (const float*)d_in[5];
    const float* bv  = (const float*)d_in[6];
    const float* wo  = (const float*)d_in[7];
    const float* bo  = (const float*)d_in[8];
    const float* g1  = (const float*)d_in[9];
    const float* e1  = (const float*)d_in[10];
    const float* w1  = (const float*)d_in[11];
    const float* b1  = (const float*)d_in[12];
    const float* w2  = (const float*)d_in[13];
    const float* b2  = (const float*)d_in[14];
    const float* g2  = (const float*)d_in[15];
    const float* e2  = (const float*)d_in[16];

    float* F = (float*)d_ws;
    size_t off = 0;
    float* xnf   = F + off; off += NX;
    u16*   xnb   = (u16*)(F + off); off += NX / 2;
    u16*   qkvb  = (u16*)(F + off); off += (size_t)NTOK * 3 * DM / 2;
    u16*   vTb   = (u16*)(F + off); off += (size_t)NTOK * DM / 2;   // vT[bh][d][tok]
    float* y     = F + off; off += NX;
    u16*   aob   = (u16*)(F + off); off += NX / 2;
    u16*   hb    = (u16*)(F + off); off += (size_t)NTOK * HM / 2;
    u16*   wqkvb = (u16*)(F + off); off += (size_t)3 * DM * DM / 2;
    u16*   wob   = (u16*)(F + off); off += (size_t)DM * DM / 2;
    u16*   w1b   = (u16*)(F + off); off += (size_t)HM * DM / 2;
    u16*   w2b   = (u16*)(F + off); off += (size_t)DM * HM / 2;
    float* bqkv  = F + off; off += 3 * DM;
    if (ws_size < off * sizeof(float)) return;

    dim3 blk(256);
    cvt_all<<<(12 * DM * DM / 4 + 3 * DM + 255) / 256, blk, 0, stream>>>(
        wq, wk, wv, wo, w1, w2, bq, bk, bv, bqkv, wqkvb);

    // xn1 = LN1(x)
    ln_kernel<<<NTOK, blk, 0, stream>>>(x, g1, e1, xnf, xnb);
    // qkv = xn1 @ [qs*wq|wk|wv]^T + b   (bf16 out)
    gemm_bt<0,0,1><<<dim3(3 * DM / 128, NTOK / 128), blk, 0, stream>>>(
        xnb, wqkvb, bqkv, nullptr, qkvb, NTOK, 3 * DM, DM);
    // vT = transpose(V region)
    vtr_kernel<<<NBATCH * NHEADS * (SQ / 64), blk, 0, stream>>>(qkvb, vTb);
    // aob = softmax(q k^T) v
    fattn_mfma<<<NBATCH * NHEADS * (SQ / 64), blk, 0, stream>>>(qkvb, vTb, aob);
    // y = xn1 + aob @ wo^T + bo
    gemm_n64<0,1,0><<<dim3(DM / 64, NTOK / 128), blk, 0, stream>>>(
        aob, wob, bo, xnf, y, NTOK, DM, DM);
    // xn2 = LN2(y)
    ln_kernel<<<NTOK, blk, 0, stream>>>(y, g2, e2, xnf, xnb);
    // hb = gelu(xn2 @ w1^T + b1)   (bf16 out)
    gemm_bt<1,0,1><<<dim3(HM / 128, NTOK / 128), blk, 0, stream>>>(
        xnb, w1b, b1, nullptr, hb, NTOK, HM, DM);
    // out = xn2 + hb @ w2^T + b2   (fp32 out)
    gemm_n64<0,1,0><<<dim3(DM / 64, NTOK / 128), blk, 0, stream>>>(
        hb, w2b, b2, xnf, d_out, NTOK, DM, HM);
}

// Round 11
// 357.119 us; speedup vs baseline: 1.0961x; 1.0331x over previous
//
#include <hip/hip_runtime.h>
#include <hip/hip_bf16.h>

typedef unsigned short u16;
typedef __attribute__((ext_vector_type(8))) short short8;   // 8 bf16 (4 VGPRs)
typedef __attribute__((ext_vector_type(4))) float f32x4;    // 4 fp32 acc

#define DM 1024      // d_model
#define HM 4096      // ffn hidden
#define NHEADS 16
#define HD 64        // head dim
#define SQ 2048      // seq len
#define NBATCH 2
#define NTOK 4096    // NBATCH*SQ

#define NX  ((size_t)NTOK * DM)

__device__ __forceinline__ u16 f2b(float f) {   // fp32 -> bf16 RNE
    union { float f; unsigned int i; } w; w.f = f;
    unsigned int x = w.i;
    return (u16)((x + 0x7FFFu + ((x >> 16) & 1u)) >> 16);
}

__device__ __forceinline__ void gload_lds16(const void* g, void* l) {
    __builtin_amdgcn_global_load_lds(
        (const __attribute__((address_space(1))) void*)g,
        (__attribute__((address_space(3))) void*)l, 16, 0, 0);
}

// tanh-form GELU: 0.5x(1+tanh(s(x+0.044715x^3))), tanh via single v_exp_f32
// + fast rcp. |err| vs erf-GELU ~1e-3 << bf16 quantization of hb (~4e-3).
__device__ __forceinline__ float gelu_tanh(float x) {
    float x3 = x * x * x;
    float y  = 0.7978845608028654f * fmaf(0.044715f, x3, x);
    float u  = y * 2.8853900817779268f;      // 2*log2(e)*y
    float e;
    asm("v_exp_f32 %0, %1" : "=v"(e) : "v"(u));   // e = 2^u = exp(2y)
    float th = (e - 1.0f) * __builtin_amdgcn_rcpf(e + 1.0f);
    float a  = 0.5f * x;
    return fmaf(a, th, a);
}

// ---- all weights fp32 -> bf16 + bias pack, ONE kernel ----
// dst layout (u16): wq|wk|wv (3M) | wo (1M) | w1 (4M) | w2 (4M)
// wq/bq carry 0.125*log2(e): S arrives pre-scaled for exp2 (v_exp_f32).
__global__ void cvt_all(const float* __restrict__ wq, const float* __restrict__ wk,
                        const float* __restrict__ wv, const float* __restrict__ wo,
                        const float* __restrict__ w1, const float* __restrict__ w2,
                        const float* __restrict__ bq, const float* __restrict__ bk,
                        const float* __restrict__ bv, float* __restrict__ bias_dst,
                        u16* __restrict__ dst) {
    const int NW4 = DM * DM / 4;   // float4s per DMxDM matrix
    const float QS = 0.18033688011112042f;   // 0.125 * log2(e)
    int i = blockIdx.x * 256 + threadIdx.x;
    if (i < 12 * NW4) {
        const float* src; int base; float sc = 1.0f;
        if      (i <     NW4) { src = wq; base = 0;       sc = QS; }
        else if (i < 2 * NW4) { src = wk; base = NW4; }
        else if (i < 3 * NW4) { src = wv; base = 2 * NW4; }
        else if (i < 4 * NW4) { src = wo; base = 3 * NW4; }
        else if (i < 8 * NW4) { src = w1; base = 4 * NW4; }
        else                  { src = w2; base = 8 * NW4; }
        float4 f = ((const float4*)src)[i - base];
        ushort4 o;
        o.x = f2b(f.x * sc); o.y = f2b(f.y * sc);
        o.z = f2b(f.z * sc); o.w = f2b(f.w * sc);
        ((ushort4*)dst)[i] = o;
    } else {
        int j = i - 12 * NW4;
        if (j < 3 * DM) {
            float v = (j < DM) ? bq[j] * QS
                    : (j < 2 * DM) ? bk[j - DM] : bv[j - 2 * DM];
            bias_dst[j] = v;
        }
    }
}

// ---------------- LayerNorm: fp32 in, fp32 + bf16 out ----------------
__global__ void ln_kernel(const float* __restrict__ xin, const float* __restrict__ g,
                          const float* __restrict__ b, float* __restrict__ outf,
                          u16* __restrict__ outb) {
    int t = blockIdx.x, tid = threadIdx.x;
    float4 f = ((const float4*)(xin + (size_t)t * DM))[tid];
    float v0 = f.x, v1 = f.y, v2 = f.z, v3 = f.w;
    float s  = v0 + v1 + v2 + v3;
    float ss = v0*v0 + v1*v1 + v2*v2 + v3*v3;
    #pragma unroll
    for (int o = 32; o > 0; o >>= 1) {
        s  += __shfl_down(s,  o, 64);
        ss += __shfl_down(ss, o, 64);
    }
    __shared__ float rs[4], rss[4];
    int w = tid >> 6, lane = tid & 63;
    if (!lane) { rs[w] = s; rss[w] = ss; }
    __syncthreads();
    s  = rs[0] + rs[1] + rs[2] + rs[3];
    ss = rss[0] + rss[1] + rss[2] + rss[3];
    float mean = s * (1.0f / DM);
    float var  = ss * (1.0f / DM) - mean * mean;
    float rstd = rsqrtf(var + 1e-5f);
    float4 gu = ((const float4*)g)[tid];
    float4 bu = ((const float4*)b)[tid];
    float4 o;
    o.x = (v0 - mean) * rstd * gu.x + bu.x;
    o.y = (v1 - mean) * rstd * gu.y + bu.y;
    o.z = (v2 - mean) * rstd * gu.z + bu.z;
    o.w = (v3 - mean) * rstd * gu.w + bu.w;
    ((float4*)(outf + (size_t)t * DM))[tid] = o;
    ushort4 ob; ob.x = f2b(o.x); ob.y = f2b(o.y); ob.z = f2b(o.z); ob.w = f2b(o.w);
    ((ushort4*)(outb + (size_t)t * DM))[tid] = ob;
}

// ---- V transpose: qkv V-region [tok][h*64+d] -> vT[b*16+h][d][tok_in_batch] ----
__global__ void vtr_kernel(const u16* __restrict__ qkv, u16* __restrict__ vT) {
    __shared__ u16 tile[64][72];
    int bid = blockIdx.x;          // 32 bh x 32 t-tiles
    int tt = bid & 31, bh = bid >> 5;
    int h = bh & (NHEADS - 1), b = bh >> 4;
    int tid = threadIdx.x;
    int r = tid >> 2, c0 = (tid & 3) << 4;
    const u16* src = qkv + ((size_t)(b * SQ + tt * 64 + r)) * (3 * DM) + 2 * DM + h * HD + c0;
    #pragma unroll
    for (int j = 0; j < 4; j++)
        *(ushort4*)&tile[r][c0 + (j << 2)] = *(const ushort4*)(src + (j << 2));
    __syncthreads();
    int dd = tid >> 2, t0 = (tid & 3) << 4;
    u16* dst = vT + ((size_t)bh * HD + dd) * SQ + tt * 64 + t0;
    #pragma unroll
    for (int j = 0; j < 4; j++) {
        ushort4 v;
        v.x = tile[t0 + (j << 2) + 0][dd];
        v.y = tile[t0 + (j << 2) + 1][dd];
        v.z = tile[t0 + (j << 2) + 2][dd];
        v.w = tile[t0 + (j << 2) + 3][dd];
        *(ushort4*)(dst + (j << 2)) = v;
    }
}

// ------- MFMA GEMM 128x128, BK=64, dbuf + 8-way XOR chunk swizzle -------
template<int GELU, int RESID, int OUTBF>
__global__ __launch_bounds__(256, 2)
void gemm_bt(const u16* __restrict__ A, const u16* __restrict__ W,
             const float* __restrict__ bias, const float* __restrict__ resid,
             void* __restrict__ Cout, int M, int N, int K) {
    __shared__ __attribute__((aligned(16))) u16 As[2 * 128 * 64];   // 32 KB
    __shared__ __attribute__((aligned(16))) u16 Bs[2 * 128 * 64];   // 32 KB
    int tid  = threadIdx.x;
    int wid  = tid >> 6, lane = tid & 63;
    int m0 = blockIdx.y << 7, n0 = blockIdx.x << 7;
    int wm = (wid & 1) << 6, wn = (wid >> 1) << 6;

    int rIn = lane >> 3;
    int cSw = (((lane & 7) ^ (lane >> 3)) << 3);          // swizzled source chunk
    int s0  = wid << 2;
    int fr = lane & 15;
    int ksw0 = (((lane >> 4) ^ (lane & 7)) << 3);         // ch=0 swizzled k-off
    int ksw1 = (((4 + (lane >> 4)) ^ (lane & 7)) << 3);   // ch=1

    f32x4 acc[4][4];
    #pragma unroll
    for (int i = 0; i < 4; i++)
        #pragma unroll
        for (int j = 0; j < 4; j++)
            acc[i][j] = (f32x4){0.f, 0.f, 0.f, 0.f};

    // prologue: stage K-tile 0 into buf 0
    #pragma unroll
    for (int t = 0; t < 4; t++) {
        int s = s0 + t;
        gload_lds16(A + (size_t)(m0 + (s << 3) + rIn) * K + cSw, As + (s << 9));
        gload_lds16(W + (size_t)(n0 + (s << 3) + rIn) * K + cSw, Bs + (s << 9));
    }
    __syncthreads();

    int nk = K >> 6;
    for (int kt = 0; kt < nk; kt++) {
        int buf = kt & 1;
        const u16* Ab = As + (buf << 13);
        const u16* Bb = Bs + (buf << 13);
        if (kt + 1 < nk) {              // prefetch next tile into other buffer
            int k0 = (kt + 1) << 6;
            int bo = (buf ^ 1) << 13;
            #pragma unroll
            for (int t = 0; t < 4; t++) {
                int s = s0 + t;
                gload_lds16(A + (size_t)(m0 + (s << 3) + rIn) * K + k0 + cSw, As + bo + (s << 9));
                gload_lds16(W + (size_t)(n0 + (s << 3) + rIn) * K + k0 + cSw, Bs + bo + (s << 9));
            }
        }
        #pragma unroll
        for (int ch = 0; ch < 2; ch++) {
            int ks = ch ? ksw1 : ksw0;
            short8 af[4], bf[4];
            #pragma unroll
            for (int mi = 0; mi < 4; mi++)
                af[mi] = *(const short8*)(Ab + (size_t)(wm + (mi << 4) + fr) * 64 + ks);
            #pragma unroll
            for (int ni = 0; ni < 4; ni++)
                bf[ni] = *(const short8*)(Bb + (size_t)(wn + (ni << 4) + fr) * 64 + ks);
            #pragma unroll
            for (int mi = 0; mi < 4; mi++)
                #pragma unroll
                for (int ni = 0; ni < 4; ni++)
                    acc[mi][ni] = __builtin_amdgcn_mfma_f32_16x16x32_bf16(
                        af[mi], bf[ni], acc[mi][ni], 0, 0, 0);
        }
        __syncthreads();   // prefetch drained (compiler vmcnt) + buf reads done
    }

    int erow = (lane >> 4) << 2;
    #pragma unroll
    for (int ni = 0; ni < 4; ni++) {
        int col = n0 + wn + (ni << 4) + fr;
        float bv = bias[col];
        #pragma unroll
        for (int mi = 0; mi < 4; mi++) {
            #pragma unroll
            for (int r = 0; r < 4; r++) {
                int row = m0 + wm + (mi << 4) + erow + r;
                float val = acc[mi][ni][r] + bv;
                if (GELU)  val = gelu_tanh(val);
                if (RESID) val += resid[(size_t)row * N + col];
                if (OUTBF) ((u16*)Cout)[(size_t)row * N + col] = f2b(val);
                else       ((float*)Cout)[(size_t)row * N + col] = val;
            }
        }
    }
}

// ------- MFMA GEMM 128x64, BK=64, dbuf + 8-way XOR chunk swizzle -------
// XCD swizzle kept: B-operand (<=2 MB) is L2-resident per XCD.
template<int GELU, int RESID, int OUTBF>
__global__ __launch_bounds__(256, 3)
void gemm_n64(const u16* __restrict__ A, const u16* __restrict__ W,
              const float* __restrict__ bias, const float* __restrict__ resid,
              void* __restrict__ Cout, int M, int N, int K) {
    __shared__ __attribute__((aligned(16))) u16 As[2 * 128 * 64];   // 32 KB
    __shared__ __attribute__((aligned(16))) u16 Bs[2 * 64 * 64];    // 16 KB
    int tid  = threadIdx.x;
    int wid  = tid >> 6, lane = tid & 63;
    int nwgx = gridDim.x;
    int bidl = blockIdx.y * nwgx + blockIdx.x;
    int cpx  = (nwgx * gridDim.y) >> 3;
    int swz  = (bidl & 7) * cpx + (bidl >> 3);
    int m0 = (swz / nwgx) << 7, n0 = (swz % nwgx) << 6;
    int wm = (wid & 1) << 6, wn = (wid >> 1) << 5;

    int rIn = lane >> 3;
    int cSw = (((lane & 7) ^ (lane >> 3)) << 3);
    int sA = wid << 2;
    int sB = wid << 1;
    int fr = lane & 15;
    int ksw0 = (((lane >> 4) ^ (lane & 7)) << 3);
    int ksw1 = (((4 + (lane >> 4)) ^ (lane & 7)) << 3);

    f32x4 acc[4][2];
    #pragma unroll
    for (int i = 0; i < 4; i++)
        #pragma unroll
        for (int j = 0; j < 2; j++)
            acc[i][j] = (f32x4){0.f, 0.f, 0.f, 0.f};

    // prologue: stage K-tile 0 into buf 0
    #pragma unroll
    for (int t = 0; t < 4; t++) {
        int s = sA + t;
        gload_lds16(A + (size_t)(m0 + (s << 3) + rIn) * K + cSw, As + (s << 9));
    }
    #pragma unroll
    for (int t = 0; t < 2; t++) {
        int s = sB + t;
        gload_lds16(W + (size_t)(n0 + (s << 3) + rIn) * K + cSw, Bs + (s << 9));
    }
    __syncthreads();

    int nk = K >> 6;
    for (int kt = 0; kt < nk; kt++) {
        int buf = kt & 1;
        const u16* Ab = As + (buf << 13);
        const u16* Bb = Bs + (buf << 12);
        if (kt + 1 < nk) {
            int k0 = (kt + 1) << 6;
            int boA = (buf ^ 1) << 13;
            int boB = (buf ^ 1) << 12;
            #pragma unroll
            for (int t = 0; t < 4; t++) {
                int s = sA + t;
                gload_lds16(A + (size_t)(m0 + (s << 3) + rIn) * K + k0 + cSw, As + boA + (s << 9));
            }
            #pragma unroll
            for (int t = 0; t < 2; t++) {
                int s = sB + t;
                gload_lds16(W + (size_t)(n0 + (s << 3) + rIn) * K + k0 + cSw, Bs + boB + (s << 9));
            }
        }
        #pragma unroll
        for (int ch = 0; ch < 2; ch++) {
            int ks = ch ? ksw1 : ksw0;
            short8 af[4], bf[2];
            #pragma unroll
            for (int mi = 0; mi < 4; mi++)
                af[mi] = *(const short8*)(Ab + (size_t)(wm + (mi << 4) + fr) * 64 + ks);
            #pragma unroll
            for (int ni = 0; ni < 2; ni++)
                bf[ni] = *(const short8*)(Bb + (size_t)(wn + (ni << 4) + fr) * 64 + ks);
            #pragma unroll
            for (int mi = 0; mi < 4; mi++)
                #pragma unroll
                for (int ni = 0; ni < 2; ni++)
                    acc[mi][ni] = __builtin_amdgcn_mfma_f32_16x16x32_bf16(
                        af[mi], bf[ni], acc[mi][ni], 0, 0, 0);
        }
        __syncthreads();
    }

    int erow = (lane >> 4) << 2;
    #pragma unroll
    for (int ni = 0; ni < 2; ni++) {
        int col = n0 + wn + (ni << 4) + fr;
        float bv = bias[col];
        #pragma unroll
        for (int mi = 0; mi < 4; mi++) {
            #pragma unroll
            for (int r = 0; r < 4; r++) {
                int row = m0 + wm + (mi << 4) + erow + r;
                float val = acc[mi][ni][r] + bv;
                if (GELU)  val = gelu_tanh(val);
                if (RESID) val += resid[(size_t)row * N + col];
                if (OUTBF) ((u16*)Cout)[(size_t)row * N + col] = f2b(val);
                else       ((float*)Cout)[(size_t)row * N + col] = val;
            }
        }
    }
}

// --- MFMA flash attention v8: swapped QK^T + permlane softmax + direct exp2 ---
// Q pre-scaled by log2(e) at cvt time -> P = 2^S via single v_exp_f32 (no mul).
__global__ __launch_bounds__(256) void fattn_mfma(const u16* __restrict__ QKV,
                                                  const u16* __restrict__ VT,
                                                  u16* __restrict__ O) {
    __shared__ __attribute__((aligned(16))) u16 QP[4096];        // Q tile
    __shared__ __attribute__((aligned(16))) u16 Ks[2][4096];     // dbuf [2ch][64][32]
    __shared__ __attribute__((aligned(16))) u16 Vt[2][4096];     // dbuf [2ch][64d][32k]
    const int ld = 3 * DM;
    int bid = ((blockIdx.x & 7) << 7) + (blockIdx.x >> 3);   // 1024 blocks, cpx=128
    int qt = bid & 31, bh = bid >> 5;
    int h = bh & (NHEADS - 1), b = bh >> 4;
    int tid = threadIdx.x, wid = tid >> 6, lane = tid & 63;
    int fr = lane & 15;
    int fcs = (((lane >> 4) ^ ((fr >> 1) & 3)) << 3);
    int lsw = (((lane & 3) ^ ((lane >> 3) & 3)) << 3);
    size_t tokb = (size_t)b * SQ;
    const u16* Qg  = QKV + tokb * ld + h * HD;
    const u16* Kg  = QKV + tokb * ld + DM + h * HD;
    const u16* VTg = VT + ((size_t)bh * HD) * SQ;   // [d][tok]
    int s0 = wid << 1;

    {   // stage Q tile
        #pragma unroll
        for (int t = 0; t < 2; t++) {
            int s = s0 + t;
            const u16* g = Qg + (size_t)(qt * 64 + ((s & 3) << 4) + (lane >> 2)) * ld
                         + ((s >> 2) << 5) + lsw;
            gload_lds16(g, QP + (s << 9));
        }
    }
    {   // stage K/V tile 0 into buf 0
        #pragma unroll
        for (int t = 0; t < 2; t++) {
            int s = s0 + t;
            const u16* g = Kg + (size_t)(((s & 3) << 4) + (lane >> 2)) * ld
                         + ((s >> 2) << 5) + lsw;
            gload_lds16(g, Ks[0] + (s << 9));
            const u16* gv = VTg + (size_t)(((s & 3) << 4) + (lane >> 2)) * SQ
                          + ((s >> 2) << 5) + lsw;
            gload_lds16(gv, Vt[0] + (s << 9));
        }
    }
    f32x4 oacc[4];
    #pragma unroll
    for (int di = 0; di < 4; di++) oacc[di] = (f32x4){0.f, 0.f, 0.f, 0.f};
    float lsum = 0.f;
    __syncthreads();   // Q + tile0 visible
    short8 aq0 = *(const short8*)(QP + ((wid << 4) + fr) * 32 + fcs);
    short8 aq1 = *(const short8*)(QP + 2048 + ((wid << 4) + fr) * 32 + fcs);

    for (int kt = 0; kt < SQ / 64; kt++) {
        int buf = kt & 1;
        if (kt + 1 < SQ / 64) {   // prefetch next K/V tile into buf^1
            #pragma unroll
            for (int t = 0; t < 2; t++) {
                int s = s0 + t;
                const u16* g = Kg + (size_t)((kt + 1) * 64 + ((s & 3) << 4) + (lane >> 2)) * ld
                             + ((s >> 2) << 5) + lsw;
                gload_lds16(g, Ks[buf ^ 1] + (s << 9));
                const u16* gv = VTg + (size_t)(((s & 3) << 4) + (lane >> 2)) * SQ
                              + (kt + 1) * 64 + ((s >> 2) << 5) + lsw;
                gload_lds16(gv, Vt[buf ^ 1] + (s << 9));
            }
        }
        // S^T = K Q^T: lane holds P[q=fr][k = ni*16 + hi*4 + r]; S pre-scaled by log2e
        float p[4][4];
        #pragma unroll
        for (int ni = 0; ni < 4; ni++) {
            short8 bk0 = *(const short8*)(Ks[buf] + ((ni << 4) + fr) * 32 + fcs);
            short8 bk1 = *(const short8*)(Ks[buf] + 2048 + ((ni << 4) + fr) * 32 + fcs);
            f32x4 z = (f32x4){0.f, 0.f, 0.f, 0.f};
            __builtin_amdgcn_s_setprio(1);
            z = __builtin_amdgcn_mfma_f32_16x16x32_bf16(bk0, aq0, z, 0, 0, 0);
            z = __builtin_amdgcn_mfma_f32_16x16x32_bf16(bk1, aq1, z, 0, 0, 0);
            __builtin_amdgcn_s_setprio(0);
            #pragma unroll
            for (int r = 0; r < 4; r++) {
                float e;
                asm("v_exp_f32 %0, %1" : "=v"(e) : "v"(z[r]));   // 2^S = e^(S/log2e)
                lsum += e;
                p[ni][r] = e;
            }
        }
        unsigned int W[4][2];
        #pragma unroll
        for (int ni = 0; ni < 4; ni++) {
            asm("v_cvt_pk_bf16_f32 %0, %1, %2" : "=v"(W[ni][0]) : "v"(p[ni][0]), "v"(p[ni][1]));
            asm("v_cvt_pk_bf16_f32 %0, %1, %2" : "=v"(W[ni][1]) : "v"(p[ni][2]), "v"(p[ni][3]));
        }
        union { unsigned int w[4]; short8 v; } fA0, fA1;
        #pragma unroll
        for (int w = 0; w < 2; w++) {
            unsigned int a0 = W[0][w], b0 = W[1][w];
            asm("v_permlane32_swap_b32 %0, %1" : "+v"(a0), "+v"(b0));
            asm("v_permlane16_swap_b32 %0, %1" : "+v"(a0), "+v"(b0));
            fA0.w[w] = a0; fA0.w[w + 2] = b0;
            unsigned int a1 = W[2][w], b1 = W[3][w];
            asm("v_permlane32_swap_b32 %0, %1" : "+v"(a1), "+v"(b1));
            asm("v_permlane16_swap_b32 %0, %1" : "+v"(a1), "+v"(b1));
            fA1.w[w] = a1; fA1.w[w + 2] = b1;
        }
        short8 ap0 = fA0.v, ap1 = fA1.v;
        __builtin_amdgcn_s_setprio(1);
        #pragma unroll
        for (int di = 0; di < 4; di++) {
            short8 bv0 = *(const short8*)(Vt[buf] + ((di << 4) + fr) * 32 + fcs);
            short8 bv1 = *(const short8*)(Vt[buf] + 2048 + ((di << 4) + fr) * 32 + fcs);
            oacc[di] = __builtin_amdgcn_mfma_f32_16x16x32_bf16(ap0, bv0, oacc[di], 0, 0, 0);
            oacc[di] = __builtin_amdgcn_mfma_f32_16x16x32_bf16(ap1, bv1, oacc[di], 0, 0, 0);
        }
        __builtin_amdgcn_s_setprio(0);
        __syncthreads();   // drain prefetch; protect buf swap
    }
    lsum += __shfl_xor(lsum, 16, 64);
    lsum += __shfl_xor(lsum, 32, 64);
    float inv = 1.0f / lsum;           // valid for q = fr
    float invq[4];
    #pragma unroll
    for (int r = 0; r < 4; r++)
        invq[r] = __shfl(inv, ((lane >> 4) << 2) + r, 64);   // inv for q = hi*4+r
    #pragma unroll
    for (int di = 0; di < 4; di++) {
        int d = (di << 4) + fr;
        #pragma unroll
        for (int r = 0; r < 4; r++) {
            int q = qt * 64 + (wid << 4) + ((lane >> 4) << 2) + r;
            O[(tokb + q) * DM + h * HD + d] = f2b(oacc[di][r] * invq[r]);
        }
    }
}

extern "C" void kernel_launch(void* const* d_in, const int* in_sizes, int n_in,
                              void* d_out, int out_size, void* d_ws, size_t ws_size,
                              hipStream_t stream) {
    if (n_in < 17) return;
    const float* x   = (const float*)d_in[0];
    const float* wq  = (const float*)d_in[1];
    const float* bq  = (const float*)d_in[2];
    const float* wk  = (const float*)d_in[3];
    const float* bk  = (const float*)d_in[4];
    const float* wv  = (const float*)d_in[5];
    const float* bv  = (const float*)d_in[6];
    const float* wo  = (const float*)d_in[7];
    const float* bo  = (const float*)d_in[8];
    const float* g1  = (const float*)d_in[9];
    const float* e1  = (const float*)d_in[10];
    const float* w1  = (const float*)d_in[11];
    const float* b1  = (const float*)d_in[12];
    const float* w2  = (const float*)d_in[13];
    const float* b2  = (const float*)d_in[14];
    const float* g2  = (const float*)d_in[15];
    const float* e2  = (const float*)d_in[16];

    float* F = (float*)d_ws;
    size_t off = 0;
    float* xnf   = F + off; off += NX;
    u16*   xnb   = (u16*)(F + off); off += NX / 2;
    u16*   qkvb  = (u16*)(F + off); off += (size_t)NTOK * 3 * DM / 2;
    u16*   vTb   = (u16*)(F + off); off += (size_t)NTOK * DM / 2;   // vT[bh][d][tok]
    float* y     = F + off; off += NX;
    u16*   aob   = (u16*)(F + off); off += NX / 2;
    u16*   hb    = (u16*)(F + off); off += (size_t)NTOK * HM / 2;
    u16*   wqkvb = (u16*)(F + off); off += (size_t)3 * DM * DM / 2;
    u16*   wob   = (u16*)(F + off); off += (size_t)DM * DM / 2;
    u16*   w1b   = (u16*)(F + off); off += (size_t)HM * DM / 2;
    u16*   w2b   = (u16*)(F + off); off += (size_t)DM * HM / 2;
    float* bqkv  = F + off; off += 3 * DM;
    if (ws_size < off * sizeof(float)) return;

    dim3 blk(256);
    cvt_all<<<(12 * DM * DM / 4 + 3 * DM + 255) / 256, blk, 0, stream>>>(
        wq, wk, wv, wo, w1, w2, bq, bk, bv, bqkv, wqkvb);

    // xn1 = LN1(x)
    ln_kernel<<<NTOK, blk, 0, stream>>>(x, g1, e1, xnf, xnb);
    // qkv = xn1 @ [qs*wq|wk|wv]^T + b   (bf16 out)
    gemm_bt<0,0,1><<<dim3(3 * DM / 128, NTOK / 128), blk, 0, stream>>>(
        xnb, wqkvb, bqkv, nullptr, qkvb, NTOK, 3 * DM, DM);
    // vT = transpose(V region)
    vtr_kernel<<<NBATCH * NHEADS * (SQ / 64), blk, 0, stream>>>(qkvb, vTb);
    // aob = softmax(q k^T) v
    fattn_mfma<<<NBATCH * NHEADS * (SQ / 64), blk, 0, stream>>>(qkvb, vTb, aob);
    // y = xn1 + aob @ wo^T + bo
    gemm_n64<0,1,0><<<dim3(DM / 64, NTOK / 128), blk, 0, stream>>>(
        aob, wob, bo, xnf, y, NTOK, DM, DM);
    // xn2 = LN2(y)
    ln_kernel<<<NTOK, blk, 0, stream>>>(y, g2, e2, xnf, xnb);
    // hb = gelu(xn2 @ w1^T + b1)   (bf16 out)
    gemm_bt<1,0,1><<<dim3(HM / 128, NTOK / 128), blk, 0, stream>>>(
        xnb, w1b, b1, nullptr, hb, NTOK, HM, DM);
    // out = xn2 + hb @ w2^T + b2   (fp32 out)
    gemm_n64<0,1,0><<<dim3(DM / 64, NTOK / 128), blk, 0, stream>>>(
        hb, w2b, b2, xnf, d_out, NTOK, DM, HM);
}

// Round 12
// 352.480 us; speedup vs baseline: 1.1106x; 1.0132x over previous
//
#include <hip/hip_runtime.h>
#include <hip/hip_bf16.h>

typedef unsigned short u16;
typedef __attribute__((ext_vector_type(8))) short short8;   // 8 bf16 (4 VGPRs)
typedef __attribute__((ext_vector_type(4))) float f32x4;    // 4 fp32 acc

#define DM 1024      // d_model
#define HM 4096      // ffn hidden
#define NHEADS 16
#define HD 64        // head dim
#define SQ 2048      // seq len
#define NBATCH 2
#define NTOK 4096    // NBATCH*SQ

#define NX  ((size_t)NTOK * DM)

__device__ __forceinline__ u16 f2b(float f) {   // fp32 -> bf16 RNE
    union { float f; unsigned int i; } w; w.f = f;
    unsigned int x = w.i;
    return (u16)((x + 0x7FFFu + ((x >> 16) & 1u)) >> 16);
}

__device__ __forceinline__ void gload_lds16(const void* g, void* l) {
    __builtin_amdgcn_global_load_lds(
        (const __attribute__((address_space(1))) void*)g,
        (__attribute__((address_space(3))) void*)l, 16, 0, 0);
}

// tanh-form GELU: 0.5x(1+tanh(s(x+0.044715x^3))), tanh via single v_exp_f32
// + fast rcp. |err| vs erf-GELU ~1e-3 << bf16 quantization of hb (~4e-3).
__device__ __forceinline__ float gelu_tanh(float x) {
    float x3 = x * x * x;
    float y  = 0.7978845608028654f * fmaf(0.044715f, x3, x);
    float u  = y * 2.8853900817779268f;      // 2*log2(e)*y
    float e;
    asm("v_exp_f32 %0, %1" : "=v"(e) : "v"(u));   // e = 2^u = exp(2y)
    float th = (e - 1.0f) * __builtin_amdgcn_rcpf(e + 1.0f);
    float a  = 0.5f * x;
    return fmaf(a, th, a);
}

// ---- all weights fp32 -> bf16 + bias pack, ONE kernel ----
// dst layout (u16): wq|wk|wv (3M) | wo (1M) | w1 (4M) | w2 (4M)
// wq/bq carry 0.125*log2(e): S arrives pre-scaled for exp2 (v_exp_f32).
__global__ void cvt_all(const float* __restrict__ wq, const float* __restrict__ wk,
                        const float* __restrict__ wv, const float* __restrict__ wo,
                        const float* __restrict__ w1, const float* __restrict__ w2,
                        const float* __restrict__ bq, const float* __restrict__ bk,
                        const float* __restrict__ bv, float* __restrict__ bias_dst,
                        u16* __restrict__ dst) {
    const int NW4 = DM * DM / 4;   // float4s per DMxDM matrix
    const float QS = 0.18033688011112042f;   // 0.125 * log2(e)
    int i = blockIdx.x * 256 + threadIdx.x;
    if (i < 12 * NW4) {
        const float* src; int base; float sc = 1.0f;
        if      (i <     NW4) { src = wq; base = 0;       sc = QS; }
        else if (i < 2 * NW4) { src = wk; base = NW4; }
        else if (i < 3 * NW4) { src = wv; base = 2 * NW4; }
        else if (i < 4 * NW4) { src = wo; base = 3 * NW4; }
        else if (i < 8 * NW4) { src = w1; base = 4 * NW4; }
        else                  { src = w2; base = 8 * NW4; }
        float4 f = ((const float4*)src)[i - base];
        ushort4 o;
        o.x = f2b(f.x * sc); o.y = f2b(f.y * sc);
        o.z = f2b(f.z * sc); o.w = f2b(f.w * sc);
        ((ushort4*)dst)[i] = o;
    } else {
        int j = i - 12 * NW4;
        if (j < 3 * DM) {
            float v = (j < DM) ? bq[j] * QS
                    : (j < 2 * DM) ? bk[j - DM] : bv[j - 2 * DM];
            bias_dst[j] = v;
        }
    }
}

// ---------------- LayerNorm: fp32 in, fp32 + bf16 out ----------------
__global__ void ln_kernel(const float* __restrict__ xin, const float* __restrict__ g,
                          const float* __restrict__ b, float* __restrict__ outf,
                          u16* __restrict__ outb) {
    int t = blockIdx.x, tid = threadIdx.x;
    float4 f = ((const float4*)(xin + (size_t)t * DM))[tid];
    float v0 = f.x, v1 = f.y, v2 = f.z, v3 = f.w;
    float s  = v0 + v1 + v2 + v3;
    float ss = v0*v0 + v1*v1 + v2*v2 + v3*v3;
    #pragma unroll
    for (int o = 32; o > 0; o >>= 1) {
        s  += __shfl_down(s,  o, 64);
        ss += __shfl_down(ss, o, 64);
    }
    __shared__ float rs[4], rss[4];
    int w = tid >> 6, lane = tid & 63;
    if (!lane) { rs[w] = s; rss[w] = ss; }
    __syncthreads();
    s  = rs[0] + rs[1] + rs[2] + rs[3];
    ss = rss[0] + rss[1] + rss[2] + rss[3];
    float mean = s * (1.0f / DM);
    float var  = ss * (1.0f / DM) - mean * mean;
    float rstd = rsqrtf(var + 1e-5f);
    float4 gu = ((const float4*)g)[tid];
    float4 bu = ((const float4*)b)[tid];
    float4 o;
    o.x = (v0 - mean) * rstd * gu.x + bu.x;
    o.y = (v1 - mean) * rstd * gu.y + bu.y;
    o.z = (v2 - mean) * rstd * gu.z + bu.z;
    o.w = (v3 - mean) * rstd * gu.w + bu.w;
    ((float4*)(outf + (size_t)t * DM))[tid] = o;
    ushort4 ob; ob.x = f2b(o.x); ob.y = f2b(o.y); ob.z = f2b(o.z); ob.w = f2b(o.w);
    ((ushort4*)(outb + (size_t)t * DM))[tid] = ob;
}

// ---- V transpose: qkv V-region [tok][h*64+d] -> vT[b*16+h][d][tok_in_batch] ----
__global__ void vtr_kernel(const u16* __restrict__ qkv, u16* __restrict__ vT) {
    __shared__ u16 tile[64][72];
    int bid = blockIdx.x;          // 32 bh x 32 t-tiles
    int tt = bid & 31, bh = bid >> 5;
    int h = bh & (NHEADS - 1), b = bh >> 4;
    int tid = threadIdx.x;
    int r = tid >> 2, c0 = (tid & 3) << 4;
    const u16* src = qkv + ((size_t)(b * SQ + tt * 64 + r)) * (3 * DM) + 2 * DM + h * HD + c0;
    #pragma unroll
    for (int j = 0; j < 4; j++)
        *(ushort4*)&tile[r][c0 + (j << 2)] = *(const ushort4*)(src + (j << 2));
    __syncthreads();
    int dd = tid >> 2, t0 = (tid & 3) << 4;
    u16* dst = vT + ((size_t)bh * HD + dd) * SQ + tt * 64 + t0;
    #pragma unroll
    for (int j = 0; j < 4; j++) {
        ushort4 v;
        v.x = tile[t0 + (j << 2) + 0][dd];
        v.y = tile[t0 + (j << 2) + 1][dd];
        v.z = tile[t0 + (j << 2) + 2][dd];
        v.w = tile[t0 + (j << 2) + 3][dd];
        *(ushort4*)(dst + (j << 2)) = v;
    }
}

// ------- MFMA GEMM 128x128, BK=64, dbuf + 8-way XOR chunk swizzle -------
template<int GELU, int RESID, int OUTBF>
__global__ __launch_bounds__(256, 2)
void gemm_bt(const u16* __restrict__ A, const u16* __restrict__ W,
             const float* __restrict__ bias, const float* __restrict__ resid,
             void* __restrict__ Cout, int M, int N, int K) {
    __shared__ __attribute__((aligned(16))) u16 As[2 * 128 * 64];   // 32 KB
    __shared__ __attribute__((aligned(16))) u16 Bs[2 * 128 * 64];   // 32 KB
    int tid  = threadIdx.x;
    int wid  = tid >> 6, lane = tid & 63;
    int m0 = blockIdx.y << 7, n0 = blockIdx.x << 7;
    int wm = (wid & 1) << 6, wn = (wid >> 1) << 6;

    int rIn = lane >> 3;
    int cSw = (((lane & 7) ^ (lane >> 3)) << 3);          // swizzled source chunk
    int s0  = wid << 2;
    int fr = lane & 15;
    int ksw0 = (((lane >> 4) ^ (lane & 7)) << 3);         // ch=0 swizzled k-off
    int ksw1 = (((4 + (lane >> 4)) ^ (lane & 7)) << 3);   // ch=1

    f32x4 acc[4][4];
    #pragma unroll
    for (int i = 0; i < 4; i++)
        #pragma unroll
        for (int j = 0; j < 4; j++)
            acc[i][j] = (f32x4){0.f, 0.f, 0.f, 0.f};

    // prologue: stage K-tile 0 into buf 0
    #pragma unroll
    for (int t = 0; t < 4; t++) {
        int s = s0 + t;
        gload_lds16(A + (size_t)(m0 + (s << 3) + rIn) * K + cSw, As + (s << 9));
        gload_lds16(W + (size_t)(n0 + (s << 3) + rIn) * K + cSw, Bs + (s << 9));
    }
    __syncthreads();

    int nk = K >> 6;
    for (int kt = 0; kt < nk; kt++) {
        int buf = kt & 1;
        const u16* Ab = As + (buf << 13);
        const u16* Bb = Bs + (buf << 13);
        if (kt + 1 < nk) {              // prefetch next tile into other buffer
            int k0 = (kt + 1) << 6;
            int bo = (buf ^ 1) << 13;
            #pragma unroll
            for (int t = 0; t < 4; t++) {
                int s = s0 + t;
                gload_lds16(A + (size_t)(m0 + (s << 3) + rIn) * K + k0 + cSw, As + bo + (s << 9));
                gload_lds16(W + (size_t)(n0 + (s << 3) + rIn) * K + k0 + cSw, Bs + bo + (s << 9));
            }
        }
        #pragma unroll
        for (int ch = 0; ch < 2; ch++) {
            int ks = ch ? ksw1 : ksw0;
            short8 af[4], bf[4];
            #pragma unroll
            for (int mi = 0; mi < 4; mi++)
                af[mi] = *(const short8*)(Ab + (size_t)(wm + (mi << 4) + fr) * 64 + ks);
            #pragma unroll
            for (int ni = 0; ni < 4; ni++)
                bf[ni] = *(const short8*)(Bb + (size_t)(wn + (ni << 4) + fr) * 64 + ks);
            #pragma unroll
            for (int mi = 0; mi < 4; mi++)
                #pragma unroll
                for (int ni = 0; ni < 4; ni++)
                    acc[mi][ni] = __builtin_amdgcn_mfma_f32_16x16x32_bf16(
                        af[mi], bf[ni], acc[mi][ni], 0, 0, 0);
        }
        __syncthreads();   // prefetch drained (compiler vmcnt) + buf reads done
    }

    int erow = (lane >> 4) << 2;
    #pragma unroll
    for (int ni = 0; ni < 4; ni++) {
        int col = n0 + wn + (ni << 4) + fr;
        float bv = bias[col];
        #pragma unroll
        for (int mi = 0; mi < 4; mi++) {
            #pragma unroll
            for (int r = 0; r < 4; r++) {
                int row = m0 + wm + (mi << 4) + erow + r;
                float val = acc[mi][ni][r] + bv;
                if (GELU)  val = gelu_tanh(val);
                if (RESID) val += resid[(size_t)row * N + col];
                if (OUTBF) ((u16*)Cout)[(size_t)row * N + col] = f2b(val);
                else       ((float*)Cout)[(size_t)row * N + col] = val;
            }
        }
    }
}

// ------- MFMA GEMM 64x64, BK=64, dbuf + 8-way XOR chunk swizzle -------
// Small-N GEMMs (N=1024) were grid-limited to 2 blocks/CU at 128x64 (R11:
// Occupancy 20%, latency-bound). 64x64 doubles grid to 1024 = 4 blocks/CU.
// No XCD swizzle: measured neutral (R5 vs R11), and FFN-down's B (8 MB)
// exceeds per-XCD L2 so m-major chunking would thrash (R6 lesson).
template<int GELU, int RESID, int OUTBF>
__global__ __launch_bounds__(256, 4)
void gemm_n64(const u16* __restrict__ A, const u16* __restrict__ W,
              const float* __restrict__ bias, const float* __restrict__ resid,
              void* __restrict__ Cout, int M, int N, int K) {
    __shared__ __attribute__((aligned(16))) u16 As[2 * 64 * 64];    // 16 KB
    __shared__ __attribute__((aligned(16))) u16 Bs[2 * 64 * 64];    // 16 KB
    int tid  = threadIdx.x;
    int wid  = tid >> 6, lane = tid & 63;
    int m0 = blockIdx.y << 6, n0 = blockIdx.x << 6;
    int wm = (wid & 1) << 5, wn = (wid >> 1) << 5;

    int rIn = lane >> 3;
    int cSw = (((lane & 7) ^ (lane >> 3)) << 3);
    int sA = wid << 1;                    // 2 of 8 segs per wave (A and B)
    int fr = lane & 15;
    int ksw0 = (((lane >> 4) ^ (lane & 7)) << 3);
    int ksw1 = (((4 + (lane >> 4)) ^ (lane & 7)) << 3);

    f32x4 acc[2][2];
    #pragma unroll
    for (int i = 0; i < 2; i++)
        #pragma unroll
        for (int j = 0; j < 2; j++)
            acc[i][j] = (f32x4){0.f, 0.f, 0.f, 0.f};

    // prologue: stage K-tile 0 into buf 0
    #pragma unroll
    for (int t = 0; t < 2; t++) {
        int s = sA + t;
        gload_lds16(A + (size_t)(m0 + (s << 3) + rIn) * K + cSw, As + (s << 9));
        gload_lds16(W + (size_t)(n0 + (s << 3) + rIn) * K + cSw, Bs + (s << 9));
    }
    __syncthreads();

    int nk = K >> 6;
    for (int kt = 0; kt < nk; kt++) {
        int buf = kt & 1;
        const u16* Ab = As + (buf << 12);
        const u16* Bb = Bs + (buf << 12);
        if (kt + 1 < nk) {
            int k0 = (kt + 1) << 6;
            int bo = (buf ^ 1) << 12;
            #pragma unroll
            for (int t = 0; t < 2; t++) {
                int s = sA + t;
                gload_lds16(A + (size_t)(m0 + (s << 3) + rIn) * K + k0 + cSw, As + bo + (s << 9));
                gload_lds16(W + (size_t)(n0 + (s << 3) + rIn) * K + k0 + cSw, Bs + bo + (s << 9));
            }
        }
        #pragma unroll
        for (int ch = 0; ch < 2; ch++) {
            int ks = ch ? ksw1 : ksw0;
            short8 af[2], bf[2];
            #pragma unroll
            for (int mi = 0; mi < 2; mi++)
                af[mi] = *(const short8*)(Ab + (size_t)(wm + (mi << 4) + fr) * 64 + ks);
            #pragma unroll
            for (int ni = 0; ni < 2; ni++)
                bf[ni] = *(const short8*)(Bb + (size_t)(wn + (ni << 4) + fr) * 64 + ks);
            #pragma unroll
            for (int mi = 0; mi < 2; mi++)
                #pragma unroll
                for (int ni = 0; ni < 2; ni++)
                    acc[mi][ni] = __builtin_amdgcn_mfma_f32_16x16x32_bf16(
                        af[mi], bf[ni], acc[mi][ni], 0, 0, 0);
        }
        __syncthreads();
    }

    int erow = (lane >> 4) << 2;
    #pragma unroll
    for (int ni = 0; ni < 2; ni++) {
        int col = n0 + wn + (ni << 4) + fr;
        float bv = bias[col];
        #pragma unroll
        for (int mi = 0; mi < 2; mi++) {
            #pragma unroll
            for (int r = 0; r < 4; r++) {
                int row = m0 + wm + (mi << 4) + erow + r;
                float val = acc[mi][ni][r] + bv;
                if (GELU)  val = gelu_tanh(val);
                if (RESID) val += resid[(size_t)row * N + col];
                if (OUTBF) ((u16*)Cout)[(size_t)row * N + col] = f2b(val);
                else       ((float*)Cout)[(size_t)row * N + col] = val;
            }
        }
    }
}

// --- MFMA flash attention v8: swapped QK^T + permlane softmax + direct exp2 ---
// Q pre-scaled by log2(e) at cvt time -> P = 2^S via single v_exp_f32 (no mul).
__global__ __launch_bounds__(256) void fattn_mfma(const u16* __restrict__ QKV,
                                                  const u16* __restrict__ VT,
                                                  u16* __restrict__ O) {
    __shared__ __attribute__((aligned(16))) u16 QP[4096];        // Q tile
    __shared__ __attribute__((aligned(16))) u16 Ks[2][4096];     // dbuf [2ch][64][32]
    __shared__ __attribute__((aligned(16))) u16 Vt[2][4096];     // dbuf [2ch][64d][32k]
    const int ld = 3 * DM;
    int bid = ((blockIdx.x & 7) << 7) + (blockIdx.x >> 3);   // 1024 blocks, cpx=128
    int qt = bid & 31, bh = bid >> 5;
    int h = bh & (NHEADS - 1), b = bh >> 4;
    int tid = threadIdx.x, wid = tid >> 6, lane = tid & 63;
    int fr = lane & 15;
    int fcs = (((lane >> 4) ^ ((fr >> 1) & 3)) << 3);
    int lsw = (((lane & 3) ^ ((lane >> 3) & 3)) << 3);
    size_t tokb = (size_t)b * SQ;
    const u16* Qg  = QKV + tokb * ld + h * HD;
    const u16* Kg  = QKV + tokb * ld + DM + h * HD;
    const u16* VTg = VT + ((size_t)bh * HD) * SQ;   // [d][tok]
    int s0 = wid << 1;

    {   // stage Q tile
        #pragma unroll
        for (int t = 0; t < 2; t++) {
            int s = s0 + t;
            const u16* g = Qg + (size_t)(qt * 64 + ((s & 3) << 4) + (lane >> 2)) * ld
                         + ((s >> 2) << 5) + lsw;
            gload_lds16(g, QP + (s << 9));
        }
    }
    {   // stage K/V tile 0 into buf 0
        #pragma unroll
        for (int t = 0; t < 2; t++) {
            int s = s0 + t;
            const u16* g = Kg + (size_t)(((s & 3) << 4) + (lane >> 2)) * ld
                         + ((s >> 2) << 5) + lsw;
            gload_lds16(g, Ks[0] + (s << 9));
            const u16* gv = VTg + (size_t)(((s & 3) << 4) + (lane >> 2)) * SQ
                          + ((s >> 2) << 5) + lsw;
            gload_lds16(gv, Vt[0] + (s << 9));
        }
    }
    f32x4 oacc[4];
    #pragma unroll
    for (int di = 0; di < 4; di++) oacc[di] = (f32x4){0.f, 0.f, 0.f, 0.f};
    float lsum = 0.f;
    __syncthreads();   // Q + tile0 visible
    short8 aq0 = *(const short8*)(QP + ((wid << 4) + fr) * 32 + fcs);
    short8 aq1 = *(const short8*)(QP + 2048 + ((wid << 4) + fr) * 32 + fcs);

    for (int kt = 0; kt < SQ / 64; kt++) {
        int buf = kt & 1;
        if (kt + 1 < SQ / 64) {   // prefetch next K/V tile into buf^1
            #pragma unroll
            for (int t = 0; t < 2; t++) {
                int s = s0 + t;
                const u16* g = Kg + (size_t)((kt + 1) * 64 + ((s & 3) << 4) + (lane >> 2)) * ld
                             + ((s >> 2) << 5) + lsw;
                gload_lds16(g, Ks[buf ^ 1] + (s << 9));
                const u16* gv = VTg + (size_t)(((s & 3) << 4) + (lane >> 2)) * SQ
                              + (kt + 1) * 64 + ((s >> 2) << 5) + lsw;
                gload_lds16(gv, Vt[buf ^ 1] + (s << 9));
            }
        }
        // S^T = K Q^T: lane holds P[q=fr][k = ni*16 + hi*4 + r]; S pre-scaled by log2e
        float p[4][4];
        #pragma unroll
        for (int ni = 0; ni < 4; ni++) {
            short8 bk0 = *(const short8*)(Ks[buf] + ((ni << 4) + fr) * 32 + fcs);
            short8 bk1 = *(const short8*)(Ks[buf] + 2048 + ((ni << 4) + fr) * 32 + fcs);
            f32x4 z = (f32x4){0.f, 0.f, 0.f, 0.f};
            __builtin_amdgcn_s_setprio(1);
            z = __builtin_amdgcn_mfma_f32_16x16x32_bf16(bk0, aq0, z, 0, 0, 0);
            z = __builtin_amdgcn_mfma_f32_16x16x32_bf16(bk1, aq1, z, 0, 0, 0);
            __builtin_amdgcn_s_setprio(0);
            #pragma unroll
            for (int r = 0; r < 4; r++) {
                float e;
                asm("v_exp_f32 %0, %1" : "=v"(e) : "v"(z[r]));   // 2^S = e^(S/log2e)
                lsum += e;
                p[ni][r] = e;
            }
        }
        unsigned int W[4][2];
        #pragma unroll
        for (int ni = 0; ni < 4; ni++) {
            asm("v_cvt_pk_bf16_f32 %0, %1, %2" : "=v"(W[ni][0]) : "v"(p[ni][0]), "v"(p[ni][1]));
            asm("v_cvt_pk_bf16_f32 %0, %1, %2" : "=v"(W[ni][1]) : "v"(p[ni][2]), "v"(p[ni][3]));
        }
        union { unsigned int w[4]; short8 v; } fA0, fA1;
        #pragma unroll
        for (int w = 0; w < 2; w++) {
            unsigned int a0 = W[0][w], b0 = W[1][w];
            asm("v_permlane32_swap_b32 %0, %1" : "+v"(a0), "+v"(b0));
            asm("v_permlane16_swap_b32 %0, %1" : "+v"(a0), "+v"(b0));
            fA0.w[w] = a0; fA0.w[w + 2] = b0;
            unsigned int a1 = W[2][w], b1 = W[3][w];
            asm("v_permlane32_swap_b32 %0, %1" : "+v"(a1), "+v"(b1));
            asm("v_permlane16_swap_b32 %0, %1" : "+v"(a1), "+v"(b1));
            fA1.w[w] = a1; fA1.w[w + 2] = b1;
        }
        short8 ap0 = fA0.v, ap1 = fA1.v;
        __builtin_amdgcn_s_setprio(1);
        #pragma unroll
        for (int di = 0; di < 4; di++) {
            short8 bv0 = *(const short8*)(Vt[buf] + ((di << 4) + fr) * 32 + fcs);
            short8 bv1 = *(const short8*)(Vt[buf] + 2048 + ((di << 4) + fr) * 32 + fcs);
            oacc[di] = __builtin_amdgcn_mfma_f32_16x16x32_bf16(ap0, bv0, oacc[di], 0, 0, 0);
            oacc[di] = __builtin_amdgcn_mfma_f32_16x16x32_bf16(ap1, bv1, oacc[di], 0, 0, 0);
        }
        __builtin_amdgcn_s_setprio(0);
        __syncthreads();   // drain prefetch; protect buf swap
    }
    lsum += __shfl_xor(lsum, 16, 64);
    lsum += __shfl_xor(lsum, 32, 64);
    float inv = 1.0f / lsum;           // valid for q = fr
    float invq[4];
    #pragma unroll
    for (int r = 0; r < 4; r++)
        invq[r] = __shfl(inv, ((lane >> 4) << 2) + r, 64);   // inv for q = hi*4+r
    #pragma unroll
    for (int di = 0; di < 4; di++) {
        int d = (di << 4) + fr;
        #pragma unroll
        for (int r = 0; r < 4; r++) {
            int q = qt * 64 + (wid << 4) + ((lane >> 4) << 2) + r;
            O[(tokb + q) * DM + h * HD + d] = f2b(oacc[di][r] * invq[r]);
        }
    }
}

extern "C" void kernel_launch(void* const* d_in, const int* in_sizes, int n_in,
                              void* d_out, int out_size, void* d_ws, size_t ws_size,
                              hipStream_t stream) {
    if (n_in < 17) return;
    const float* x   = (const float*)d_in[0];
    const float* wq  = (const float*)d_in[1];
    const float* bq  = (const float*)d_in[2];
    const float* wk  = (const float*)d_in[3];
    const float* bk  = (const float*)d_in[4];
    const float* wv  = (const float*)d_in[5];
    const float* bv  = (const float*)d_in[6];
    const float* wo  = (const float*)d_in[7];
    const float* bo  = (const float*)d_in[8];
    const float* g1  = (const float*)d_in[9];
    const float* e1  = (const float*)d_in[10];
    const float* w1  = (const float*)d_in[11];
    const float* b1  = (const float*)d_in[12];
    const float* w2  = (const float*)d_in[13];
    const float* b2  = (const float*)d_in[14];
    const float* g2  = (const float*)d_in[15];
    const float* e2  = (const float*)d_in[16];

    float* F = (float*)d_ws;
    size_t off = 0;
    float* xnf   = F + off; off += NX;
    u16*   xnb   = (u16*)(F + off); off += NX / 2;
    u16*   qkvb  = (u16*)(F + off); off += (size_t)NTOK * 3 * DM / 2;
    u16*   vTb   = (u16*)(F + off); off += (size_t)NTOK * DM / 2;   // vT[bh][d][tok]
    float* y     = F + off; off += NX;
    u16*   aob   = (u16*)(F + off); off += NX / 2;
    u16*   hb    = (u16*)(F + off); off += (size_t)NTOK * HM / 2;
    u16*   wqkvb = (u16*)(F + off); off += (size_t)3 * DM * DM / 2;
    u16*   wob   = (u16*)(F + off); off += (size_t)DM * DM / 2;
    u16*   w1b   = (u16*)(F + off); off += (size_t)HM * DM / 2;
    u16*   w2b   = (u16*)(F + off); off += (size_t)DM * HM / 2;
    float* bqkv  = F + off; off += 3 * DM;
    if (ws_size < off * sizeof(float)) return;

    dim3 blk(256);
    cvt_all<<<(12 * DM * DM / 4 + 3 * DM + 255) / 256, blk, 0, stream>>>(
        wq, wk, wv, wo, w1, w2, bq, bk, bv, bqkv, wqkvb);

    // xn1 = LN1(x)
    ln_kernel<<<NTOK, blk, 0, stream>>>(x, g1, e1, xnf, xnb);
    // qkv = xn1 @ [qs*wq|wk|wv]^T + b   (bf16 out)
    gemm_bt<0,0,1><<<dim3(3 * DM / 128, NTOK / 128), blk, 0, stream>>>(
        xnb, wqkvb, bqkv, nullptr, qkvb, NTOK, 3 * DM, DM);
    // vT = transpose(V region)
    vtr_kernel<<<NBATCH * NHEADS * (SQ / 64), blk, 0, stream>>>(qkvb, vTb);
    // aob = softmax(q k^T) v
    fattn_mfma<<<NBATCH * NHEADS * (SQ / 64), blk, 0, stream>>>(qkvb, vTb, aob);
    // y = xn1 + aob @ wo^T + bo
    gemm_n64<0,1,0><<<dim3(DM / 64, NTOK / 64), blk, 0, stream>>>(
        aob, wob, bo, xnf, y, NTOK, DM, DM);
    // xn2 = LN2(y)
    ln_kernel<<<NTOK, blk, 0, stream>>>(y, g2, e2, xnf, xnb);
    // hb = gelu(xn2 @ w1^T + b1)   (bf16 out)
    gemm_bt<1,0,1><<<dim3(HM / 128, NTOK / 128), blk, 0, stream>>>(
        xnb, w1b, b1, nullptr, hb, NTOK, HM, DM);
    // out = xn2 + hb @ w2^T + b2   (fp32 out)
    gemm_n64<0,1,0><<<dim3(DM / 64, NTOK / 64), blk, 0, stream>>>(
        hb, w2b, b2, xnf, d_out, NTOK, DM, HM);
}